// Round 9
// baseline (1342.191 us; speedup 1.0000x reference)
//
#include <hip/hip_runtime.h>
#include <math.h>

#define BB 128
#define NN 128
#define KK 16
#define MEDGE (BB*NN*KK)   // 262144 edges
#define MNODE (BB*NN)      // 16384 nodes

typedef __bf16 bf16x8 __attribute__((ext_vector_type(8)));
typedef float  floatx16 __attribute__((ext_vector_type(16)));
typedef unsigned short u16;
typedef u16 ushort8_alias __attribute__((ext_vector_type(8)));

// ---------------------------------------------------------------- utilities

__device__ __forceinline__ unsigned ord32(float f) {
  unsigned u = __float_as_uint(f);
  return (u & 0x80000000u) ? ~u : (u | 0x80000000u);
}

__device__ __forceinline__ unsigned long long shfl_xor_u64(unsigned long long v, int m) {
  unsigned lo = (unsigned)(v & 0xffffffffull);
  unsigned hi = (unsigned)(v >> 32);
  lo = __shfl_xor(lo, m, 64);
  hi = __shfl_xor(hi, m, 64);
  return (((unsigned long long)hi) << 32) | (unsigned long long)lo;
}

__device__ __forceinline__ u16 bf16_rne_bits(float x) {
  unsigned u = __float_as_uint(x);
  return (u16)((u + 0x7FFF + ((u >> 16) & 1)) >> 16);
}

// ---------------------------------------------------------------- kNN: distances
template<int C>
__global__ __launch_bounds__(256) void dist_kernel(const float* __restrict__ x,
                                                   float* __restrict__ D) {
  constexpr int CH = (C < 64) ? C : 64;
  constexpr int NP = C / CH;
  constexpr int S = CH + 2;
  __shared__ float xs[NN * S];
  __shared__ float sq[NN];
  int b = blockIdx.x >> 2, qr = blockIdx.x & 3;
  const float* xb = x + (size_t)b * NN * C;
  int rg = threadIdx.x >> 5, cg = threadIdx.x & 31;
  int r0 = qr * 32 + rg * 4;

  float acc[4][4];
#pragma unroll
  for (int i = 0; i < 4; ++i)
#pragma unroll
    for (int j = 0; j < 4; ++j) acc[i][j] = 0.f;
  float sqacc = 0.f;

  for (int ps = 0; ps < NP; ++ps) {
    int c0 = ps * CH;
    __syncthreads();
    for (int t = threadIdx.x; t < NN * CH; t += 256) {
      int row = t / CH, c = t - row * CH;
      xs[row * S + c] = xb[(size_t)row * C + c0 + c];
    }
    __syncthreads();
    if (threadIdx.x < NN) {
      const float* xr = xs + threadIdx.x * S;
      float s = sqacc;
      for (int c = 0; c < CH; ++c) s = fmaf(xr[c], xr[c], s);
      sqacc = s;
    }
    for (int c = 0; c < CH; c += 2) {
      float2 av[4], bv[4];
#pragma unroll
      for (int i = 0; i < 4; ++i) av[i] = *(const float2*)&xs[(r0 + i) * S + c];
#pragma unroll
      for (int j = 0; j < 4; ++j) bv[j] = *(const float2*)&xs[(cg + 32 * j) * S + c];
#pragma unroll
      for (int i = 0; i < 4; ++i)
#pragma unroll
        for (int j = 0; j < 4; ++j) {
          acc[i][j] = fmaf(av[i].x, bv[j].x, acc[i][j]);
          acc[i][j] = fmaf(av[i].y, bv[j].y, acc[i][j]);
        }
    }
  }
  __syncthreads();
  if (threadIdx.x < NN) sq[threadIdx.x] = sqacc;
  __syncthreads();
#pragma unroll
  for (int i = 0; i < 4; ++i) {
    float sn = sq[r0 + i];
#pragma unroll
    for (int j = 0; j < 4; ++j) {
      int m = cg + 32 * j;
      D[((size_t)(b * NN + r0 + i)) * NN + m] = sn - 2.f * acc[i][j] + sq[m];
    }
  }
}

// ---------------------------------------------------------------- kNN: selection
__global__ __launch_bounds__(256) void select_kernel(const float* __restrict__ D,
                                                     int* __restrict__ idx) {
  int lane = threadIdx.x & 63, wv = threadIdx.x >> 6;
  int nd = blockIdx.x * 4 + wv;
  const float* dr = D + (size_t)nd * NN;
  unsigned long long key[2];
  key[0] = (((unsigned long long)ord32(dr[lane])) << 32) | (unsigned)lane;
  key[1] = (((unsigned long long)ord32(dr[lane + 64])) << 32) | (unsigned)(lane + 64);
  int* out = idx + (size_t)nd * KK;
  for (int r = 0; r < KK; ++r) {
    unsigned long long mk = key[0] < key[1] ? key[0] : key[1];
#pragma unroll
    for (int off = 32; off > 0; off >>= 1) {
      unsigned long long o = shfl_xor_u64(mk, off);
      if (o < mk) mk = o;
    }
    int wm = (int)(mk & 0xffffffffu);
    if (lane == 0) out[r] = wm;
    if ((wm & 63) == lane) key[wm >> 6] = ~0ull;
  }
}

// ---------------------------------------------------------------- node GEMM (scalar, layer-1 only)
__global__ __launch_bounds__(256) void node_gemm(const float* __restrict__ x,
                                                 const float* __restrict__ W,
                                                 float* __restrict__ p, float* __restrict__ q,
                                                 int Cin, int Cout) {
  int c = threadIdx.x;
  __shared__ float xr[128];
  for (int r = 0; r < 8; ++r) {
    int row = blockIdx.x * 8 + r;
    __syncthreads();
    for (int i = c; i < Cin; i += blockDim.x) xr[i] = x[(size_t)row * Cin + i];
    __syncthreads();
    float a = 0.f, qv = 0.f;
    for (int i = 0; i < Cin; ++i) {
      float xv = xr[i];
      a  = fmaf(xv, W[i * Cout + c], a);
      qv = fmaf(xv, W[(Cin + i) * Cout + c], qv);
    }
    p[(size_t)row * Cout + c] = a - qv;
    q[(size_t)row * Cout + c] = qv;
  }
}

// ---------------------------------------------------------------- W1 packing (MFMA node GEMM)
template<int K, int N>
__global__ __launch_bounds__(256) void pack_w1(const float* __restrict__ W1,
                                               u16* __restrict__ Wh, u16* __restrict__ Wl) {
  int t = blockIdx.x * 256 + threadIdx.x;
  if (t >= K * N) return;
  constexpr int C = N / 2;
  constexpr int NT2 = N / 32;
  int j = t & 7, lane = (t >> 3) & 63, tile = t >> 9;
  int nt = tile % NT2, kt = tile / NT2;
  int row = kt * 16 + (lane >> 5) * 8 + j;
  int col = nt * 32 + (lane & 31);
  float w;
  if (col < C) w = W1[row * C + col] - W1[(K + row) * C + col];
  else         w = W1[(K + row) * C + (col - C)];
  u16 h = bf16_rne_bits(w);
  float hf = __uint_as_float(((unsigned)h) << 16);
  Wh[t] = h;
  Wl[t] = bf16_rne_bits(w - hf);
}

// ---------------------------------------------------------------- MFMA node GEMM (layers 2,3)
template<int K, int N>
__global__ __launch_bounds__(256, 2) void node_gemm_mfma(
    const float* __restrict__ x, const u16* __restrict__ Wh, const u16* __restrict__ Wl,
    float* __restrict__ p, float* __restrict__ q) {
  constexpr int C = N / 2, KT = K / 16, NT2 = N / 32, NTQ = NT2 / 4;
  constexpr int CHK = NT2 * 64;
  __shared__ __align__(16) u16 Bst[2][2][CHK * 8];
  int tid = threadIdx.x, lane = tid & 63, wv = tid >> 6;
  int m = lane & 31, lh = lane >> 5;
  int rowBase = blockIdx.x * 32;
  const float* xr = x + (size_t)(rowBase + m) * K;

  floatx16 acc[NTQ];
#pragma unroll
  for (int nt = 0; nt < NTQ; ++nt)
#pragma unroll
    for (int r = 0; r < 16; ++r) acc[nt][r] = 0.f;

  float4 fxa[2], fxb[2];
  auto loadX = [&](int kt, int buf) {
    int c0 = kt * 16 + lh * 8;
    fxa[buf] = *(const float4*)(xr + c0);
    fxb[buf] = *(const float4*)(xr + c0 + 4);
  };
  auto stage = [&](int kt, int buf) {
    const ushort8_alias* srcH = (const ushort8_alias*)Wh + (size_t)kt * CHK;
    const ushort8_alias* srcL = (const ushort8_alias*)Wl + (size_t)kt * CHK;
    ushort8_alias* dH = (ushort8_alias*)Bst[buf][0];
    ushort8_alias* dL = (ushort8_alias*)Bst[buf][1];
    for (int i = tid; i < CHK; i += 256) { dH[i] = srcH[i]; dL[i] = srcL[i]; }
  };
  loadX(0, 0);
  stage(0, 0);
  __syncthreads();

#pragma unroll 2
  for (int kt = 0; kt < KT; ++kt) {
    int buf = kt & 1;
    if (kt + 1 < KT) { loadX(kt + 1, buf ^ 1); stage(kt + 1, buf ^ 1); }
    float hv[8];
    hv[0] = fxa[buf].x; hv[1] = fxa[buf].y; hv[2] = fxa[buf].z; hv[3] = fxa[buf].w;
    hv[4] = fxb[buf].x; hv[5] = fxb[buf].y; hv[6] = fxb[buf].z; hv[7] = fxb[buf].w;
    bf16x8 ah, al;
#pragma unroll
    for (int t = 0; t < 8; ++t) {
      __bf16 hb = (__bf16)hv[t];
      ah[t] = hb;
      al[t] = (__bf16)(hv[t] - (float)hb);
    }
#pragma unroll
    for (int nt = 0; nt < NTQ; ++nt) {
      int e = (wv * NTQ + nt) * 64 + lane;
      bf16x8 bh = __builtin_bit_cast(bf16x8, ((const ushort8_alias*)Bst[buf][0])[e]);
      bf16x8 bl = __builtin_bit_cast(bf16x8, ((const ushort8_alias*)Bst[buf][1])[e]);
      acc[nt] = __builtin_amdgcn_mfma_f32_32x32x16_bf16(ah, bh, acc[nt], 0, 0, 0);
      acc[nt] = __builtin_amdgcn_mfma_f32_32x32x16_bf16(al, bh, acc[nt], 0, 0, 0);
      acc[nt] = __builtin_amdgcn_mfma_f32_32x32x16_bf16(ah, bl, acc[nt], 0, 0, 0);
    }
    __syncthreads();
  }

#pragma unroll
  for (int nt = 0; nt < NTQ; ++nt) {
    int n = (wv * NTQ + nt) * 32 + m;
    float* dst = (n < C) ? p : q;
    int col = (n < C) ? n : n - C;
#pragma unroll
    for (int r = 0; r < 16; ++r) {
      int row = rowBase + (r & 3) + 8 * (r >> 2) + 4 * lh;
      dst[(size_t)row * C + col] = acc[nt][r];
    }
  }
}

// ---------------------------------------------------------------- BN1 stats (vectorized)
template<int C>
__global__ __launch_bounds__(256) void edge_stats1v(const float* __restrict__ p,
                                                    const float* __restrict__ q,
                                                    const float* __restrict__ b1,
                                                    const int* __restrict__ idx,
                                                    float* __restrict__ s1,
                                                    float* __restrict__ ss1) {
  constexpr int G = C / 4;
  constexpr int KL = 64 / G;
  int tid = threadIdx.x, lane = tid & 63, wv = tid >> 6;
  int nd = blockIdx.x * 4 + wv;
  int b = nd >> 7;
  int g = lane % G, kl = lane / G;

  __shared__ float sS[C], sSS[C];
  if (tid < C) { sS[tid] = 0.f; sSS[tid] = 0.f; }
  __syncthreads();

  const float* pr = p + (size_t)nd * C;
  float4 pv = *(const float4*)(pr + g * 4);
  float4 bv = *(const float4*)(b1 + g * 4);
  pv.x += bv.x; pv.y += bv.y; pv.z += bv.z; pv.w += bv.w;
  float4 s = {0, 0, 0, 0}, ss = {0, 0, 0, 0};
  const int* id = idx + (size_t)nd * KK;
#pragma unroll
  for (int k0 = 0; k0 < KK; k0 += KL) {
    int j = id[k0 + kl];
    float4 q4 = *(const float4*)(q + (size_t)(b * NN + j) * C + g * 4);
    float y;
    y = pv.x + q4.x; s.x += y; ss.x = fmaf(y, y, ss.x);
    y = pv.y + q4.y; s.y += y; ss.y = fmaf(y, y, ss.y);
    y = pv.z + q4.z; s.z += y; ss.z = fmaf(y, y, ss.z);
    y = pv.w + q4.w; s.w += y; ss.w = fmaf(y, y, ss.w);
  }
#pragma unroll
  for (int off = G; off < 64; off <<= 1) {
    s.x += __shfl_xor(s.x, off); ss.x += __shfl_xor(ss.x, off);
    s.y += __shfl_xor(s.y, off); ss.y += __shfl_xor(ss.y, off);
    s.z += __shfl_xor(s.z, off); ss.z += __shfl_xor(ss.z, off);
    s.w += __shfl_xor(s.w, off); ss.w += __shfl_xor(ss.w, off);
  }
  if (kl == 0) {
    atomicAdd(&sS[g * 4 + 0], s.x); atomicAdd(&sSS[g * 4 + 0], ss.x);
    atomicAdd(&sS[g * 4 + 1], s.y); atomicAdd(&sSS[g * 4 + 1], ss.y);
    atomicAdd(&sS[g * 4 + 2], s.z); atomicAdd(&sSS[g * 4 + 2], ss.z);
    atomicAdd(&sS[g * 4 + 3], s.w); atomicAdd(&sSS[g * 4 + 3], ss.w);
  }
  __syncthreads();
  if (tid < C) {
    atomicAdd(&s1[tid], sS[tid]);
    atomicAdd(&ss1[tid], sSS[tid]);
  }
}

// ---------------------------------------------------------------- BN params (BN1 only)
__global__ void bn_params(const float* __restrict__ s, const float* __restrict__ ss,
                          const float* __restrict__ g, const float* __restrict__ beta,
                          const float* __restrict__ bias,
                          float M, float* __restrict__ scale, float* __restrict__ shift) {
  int c = threadIdx.x;
  float mean = s[c] / M;
  float var = ss[c] / M - mean * mean;
  if (var < 0.f) var = 0.f;
  float sc = g[c] * rsqrtf(var + 1e-5f);
  scale[c] = sc;
  float sh = beta[c] - mean * sc;
  if (bias) sh += sc * bias[c];
  shift[c] = sh;
}

// ---------------------------------------------------------------- W2 packing (32x32x16)
template<int C>
__global__ __launch_bounds__(256) void pack_w2(const float* __restrict__ W,
                                               u16* __restrict__ Wh, u16* __restrict__ Wl) {
  int t = blockIdx.x * 256 + threadIdx.x;
  if (t >= C * C) return;
  constexpr int NT = C / 32;
  int j = t & 7, lane = (t >> 3) & 63, ktnt = t >> 9;
  int nt = ktnt % NT, kt = ktnt / NT;
  int row = kt * 16 + (lane >> 5) * 8 + j;
  int col = nt * 32 + (lane & 31);
  float w = W[row * C + col];
  u16 h = bf16_rne_bits(w);
  float hf = __uint_as_float(((unsigned)h) << 16);
  Wh[t] = h;
  Wl[t] = bf16_rne_bits(w - hf);
}

// ---------------------------------------------------------------- MFMA edge GEMM2 v6
// Block = 512 thr = 8 waves = 8 nodes (M=128, 4 M-tiles) x N-slice.
// A hi/lo fragments REGISTER-resident per wave (built once from p/q gather).
// B window LDS-resident (<=64 KB): C<=128 -> filled once, K-loop has ZERO
// barriers and ZERO global traffic; C=256 -> one mid-loop refill.
// Wave = (mt, ws): mt in 0..3, ws covers NTH2 n-tiles of the block's slice.
// Epilogue: per-node max/min + BN2 sum/sumsq from acc regs, LDS-reduced.
template<int C>
__global__ __launch_bounds__(512, (C == 256) ? 2 : 4) void edge_gemm2_v6(
    const float* __restrict__ p, const float* __restrict__ q,
    const int* __restrict__ idx,
    const float* __restrict__ sc1, const float* __restrict__ sh1,  // bias1 folded into sh1
    const u16* __restrict__ Wh, const u16* __restrict__ Wl,
    const float* __restrict__ b2,
    float* __restrict__ zmax, float* __restrict__ zmin,
    float* __restrict__ s2, float* __restrict__ ss2) {
  constexpr int KT = C / 16, NT = C / 32;
  constexpr int NSLICE = (C == 256) ? 2 : 1;
  constexpr int NCOL = C / NSLICE;       // 128,128,64
  constexpr int NTS = NCOL / 32;         // n-tiles per slice: 4,4,2
  constexpr int NTH2 = NTS / 2;          // n-tiles per wave: 2,2,1
  constexpr int CK = (C == 256) ? 8 : KT;  // kt per LDS window
  constexpr int NWIN = KT / CK;
  constexpr int CCH = CK * NTS * 2 * 64;   // ushort8 chunks per window (<=4096)
  __shared__ __align__(16) u16 Bst[CCH * 8];

  int tid = threadIdx.x, lane = tid & 63, wv = tid >> 6;
  int m = lane & 31, lh = lane >> 5;
  int mt = wv >> 1, ws = wv & 1;

  int bid = blockIdx.x;
  int g = bid / NSLICE, slice = bid % NSLICE;
  // XCD swizzle: 16 node-groups per batch; groups of a batch share an XCD.
  int b = (g & 7) + 8 * ((g >> 3) >> 4);
  int nodeBase = b * NN + ((g >> 3) & 15) * 8;

  int nd = nodeBase + mt * 2 + (m >> 4);
  int j = idx[(size_t)nd * KK + (m & 15)];
  const float* pr = p + (size_t)nd * C;
  const float* qr = q + (size_t)(b * NN + j) * C;

  // ---- build A (hi/lo bf16 split) into registers, once
  bf16x8 Ah[KT], Al[KT];
#pragma unroll
  for (int kt = 0; kt < KT; ++kt) {
    int c0 = kt * 16 + lh * 8;
    float4 pa = *(const float4*)(pr + c0);
    float4 pb = *(const float4*)(pr + c0 + 4);
    float4 qa = *(const float4*)(qr + c0);
    float4 qb = *(const float4*)(qr + c0 + 4);
    float4 sa = *(const float4*)(sc1 + c0);
    float4 sb = *(const float4*)(sc1 + c0 + 4);
    float4 ta = *(const float4*)(sh1 + c0);
    float4 tb = *(const float4*)(sh1 + c0 + 4);
    float hv[8];
    hv[0] = fmaxf(fmaf(pa.x + qa.x, sa.x, ta.x), 0.f);
    hv[1] = fmaxf(fmaf(pa.y + qa.y, sa.y, ta.y), 0.f);
    hv[2] = fmaxf(fmaf(pa.z + qa.z, sa.z, ta.z), 0.f);
    hv[3] = fmaxf(fmaf(pa.w + qa.w, sa.w, ta.w), 0.f);
    hv[4] = fmaxf(fmaf(pb.x + qb.x, sb.x, tb.x), 0.f);
    hv[5] = fmaxf(fmaf(pb.y + qb.y, sb.y, tb.y), 0.f);
    hv[6] = fmaxf(fmaf(pb.z + qb.z, sb.z, tb.z), 0.f);
    hv[7] = fmaxf(fmaf(pb.w + qb.w, sb.w, tb.w), 0.f);
#pragma unroll
    for (int t = 0; t < 8; ++t) {
      __bf16 hb = (__bf16)hv[t];
      Ah[kt][t] = hb;
      Al[kt][t] = (__bf16)(hv[t] - (float)hb);
    }
  }

  floatx16 acc[NTH2];
#pragma unroll
  for (int i2 = 0; i2 < NTH2; ++i2) {
    float bv = b2[slice * NCOL + (ws * NTH2 + i2) * 32 + m];
#pragma unroll
    for (int r = 0; r < 16; ++r) acc[i2][r] = bv;
  }

  // ---- K-loop over LDS windows
  for (int w = 0; w < NWIN; ++w) {
    int kt0 = w * CK;
    __syncthreads();
    for (int i = tid; i < CCH; i += 512) {
      int c = i & 63, h = (i >> 6) & 1, rest = i >> 7;
      int ntL = rest % NTS, kk = rest / NTS;
      const ushort8_alias* src = h ? (const ushort8_alias*)Wl : (const ushort8_alias*)Wh;
      ((ushort8_alias*)Bst)[i] = src[((size_t)(kt0 + kk) * NT + slice * NTS + ntL) * 64 + c];
    }
    __syncthreads();
#pragma unroll
    for (int kk = 0; kk < CK; ++kk) {
      int kt = kt0 + kk;
#pragma unroll
      for (int i2 = 0; i2 < NTH2; ++i2) {
        int ntL = ws * NTH2 + i2;
        int base = (kk * NTS + ntL) * 128 + lane;
        bf16x8 bh = __builtin_bit_cast(bf16x8, ((const ushort8_alias*)Bst)[base]);
        bf16x8 bl = __builtin_bit_cast(bf16x8, ((const ushort8_alias*)Bst)[base + 64]);
        acc[i2] = __builtin_amdgcn_mfma_f32_32x32x16_bf16(Ah[kt], bh, acc[i2], 0, 0, 0);
        acc[i2] = __builtin_amdgcn_mfma_f32_32x32x16_bf16(Al[kt], bh, acc[i2], 0, 0, 0);
        acc[i2] = __builtin_amdgcn_mfma_f32_32x32x16_bf16(Ah[kt], bl, acc[i2], 0, 0, 0);
      }
    }
  }

  // ---- epilogue (reuse LDS for stats)
  __syncthreads();
  float* sS = (float*)Bst;
  float* sSS = sS + NCOL;
  if (tid < NCOL) { sS[tid] = 0.f; sSS[tid] = 0.f; }
  __syncthreads();

#pragma unroll
  for (int i2 = 0; i2 < NTH2; ++i2) {
    float s = 0.f, ss = 0.f;
    float mxA = -INFINITY, mnA = INFINITY, mxB = -INFINITY, mnB = INFINITY;
#pragma unroll
    for (int r = 0; r < 8; ++r) {
      float z = acc[i2][r];
      s += z; ss = fmaf(z, z, ss);
      mxA = fmaxf(mxA, z); mnA = fminf(mnA, z);
    }
#pragma unroll
    for (int r = 8; r < 16; ++r) {
      float z = acc[i2][r];
      s += z; ss = fmaf(z, z, ss);
      mxB = fmaxf(mxB, z); mnB = fminf(mnB, z);
    }
    mxA = fmaxf(mxA, __shfl_xor(mxA, 32)); mnA = fminf(mnA, __shfl_xor(mnA, 32));
    mxB = fmaxf(mxB, __shfl_xor(mxB, 32)); mnB = fminf(mnB, __shfl_xor(mnB, 32));
    float sw = s + __shfl_xor(s, 32);
    float ssw = ss + __shfl_xor(ss, 32);
    if (lane < 32) {
      int colL = (ws * NTH2 + i2) * 32 + m;
      int col = slice * NCOL + colL;
      int ndA = nodeBase + 2 * mt;
      zmax[(size_t)ndA * C + col] = mxA;
      zmin[(size_t)ndA * C + col] = mnA;
      zmax[(size_t)(ndA + 1) * C + col] = mxB;
      zmin[(size_t)(ndA + 1) * C + col] = mnB;
      atomicAdd(&sS[colL], sw);
      atomicAdd(&sSS[colL], ssw);
    }
  }
  __syncthreads();
  if (tid < NCOL) {
    atomicAdd(&s2[slice * NCOL + tid], sS[tid]);
    atomicAdd(&ss2[slice * NCOL + tid], sSS[tid]);
  }
}

// ---------------------------------------------------------------- finalize (BN2 params folded in)
__global__ __launch_bounds__(256) void finalize2_kernel(const float* __restrict__ zmax,
                                                        const float* __restrict__ zmin,
                                                        const float* __restrict__ s2,
                                                        const float* __restrict__ ss2,
                                                        const float* __restrict__ g2,
                                                        const float* __restrict__ e2,
                                                        float* __restrict__ out, int Cmask) {
  int t = blockIdx.x * 256 + threadIdx.x;
  int c = t & Cmask;
  float mean = s2[c] / (float)MEDGE;
  float var = ss2[c] / (float)MEDGE - mean * mean;
  if (var < 0.f) var = 0.f;
  float scl = g2[c] * rsqrtf(var + 1e-5f);
  float shf = e2[c] - mean * scl;
  float v = (scl >= 0.f) ? zmax[t] : zmin[t];
  out[t] = fmaxf(fmaf(v, scl, shf), 0.f);
}

// ---------------------------------------------------------------- pooling
__global__ __launch_bounds__(256) void pool_kernel(const float* __restrict__ h,
                                                   float* __restrict__ pooled) {
  int b = blockIdx.x, c = threadIdx.x;
  float s = 0.f, mx = -INFINITY;
  for (int n = 0; n < NN; ++n) {
    float v = h[(size_t)(b * NN + n) * 256 + c];
    s += v;
    mx = fmaxf(mx, v);
  }
  pooled[b * 512 + c] = s * (1.f / 128.f);
  pooled[b * 512 + 256 + c] = mx;
}

// ---------------------------------------------------------------- FC tail
__global__ __launch_bounds__(256) void fc1_fused(const float* __restrict__ pooled,
                                                 const float* __restrict__ W,
                                                 const float* __restrict__ bias,
                                                 float* __restrict__ t1raw,
                                                 float* __restrict__ fs, float* __restrict__ fss) {
  int b = blockIdx.x, c = threadIdx.x;
  __shared__ float row[512];
  row[c] = pooled[b * 512 + c];
  row[c + 256] = pooled[b * 512 + 256 + c];
  __syncthreads();
  float acc = bias[c];
  for (int i = 0; i < 512; ++i) acc = fmaf(row[i], W[i * 256 + c], acc);
  t1raw[b * 256 + c] = acc;
  atomicAdd(&fs[c], acc);
  atomicAdd(&fss[c], acc * acc);
}

__global__ __launch_bounds__(256) void fc2_fused(const float* __restrict__ t1raw,
                                                 const float* __restrict__ fs,
                                                 const float* __restrict__ fss,
                                                 const float* __restrict__ g1,
                                                 const float* __restrict__ e1,
                                                 const float* __restrict__ W,
                                                 const float* __restrict__ bias,
                                                 float* __restrict__ t2raw,
                                                 float* __restrict__ gs, float* __restrict__ gss) {
  int b = blockIdx.x, c = threadIdx.x;
  __shared__ float row[256];
  {
    float mean = fs[c] / 128.f;
    float var = fss[c] / 128.f - mean * mean;
    if (var < 0.f) var = 0.f;
    float scl = g1[c] * rsqrtf(var + 1e-5f);
    float shf = e1[c] - mean * scl;
    row[c] = fmaxf(fmaf(t1raw[b * 256 + c], scl, shf), 0.f);
  }
  __syncthreads();
  if (c < 128) {
    float acc = bias[c];
    for (int i = 0; i < 256; ++i) acc = fmaf(row[i], W[i * 128 + c], acc);
    t2raw[b * 128 + c] = acc;
    atomicAdd(&gs[c], acc);
    atomicAdd(&gss[c], acc * acc);
  }
}

__global__ __launch_bounds__(256) void fc3_fused(const float* __restrict__ t2raw,
                                                 const float* __restrict__ gs,
                                                 const float* __restrict__ gss,
                                                 const float* __restrict__ g2,
                                                 const float* __restrict__ e2,
                                                 const float* __restrict__ W,
                                                 const float* __restrict__ bias,
                                                 float* __restrict__ out) {
  __shared__ float row[128 * 2];  // scl, shf per channel
  int t = threadIdx.x;
  if (t < 128) {
    float mean = gs[t] / 128.f;
    float var = gss[t] / 128.f - mean * mean;
    if (var < 0.f) var = 0.f;
    float scl = g2[t] * rsqrtf(var + 1e-5f);
    row[t] = scl;
    row[128 + t] = e2[t] - mean * scl;
  }
  __syncthreads();
  int b = t >> 1, jj = t & 1;
  float acc = bias[jj];
  for (int r = 0; r < 128; ++r) {
    float v = fmaxf(fmaf(t2raw[b * 128 + r], row[r], row[128 + r]), 0.f);
    acc = fmaf(v, W[r * 2 + jj], acc);
  }
  out[t] = acc;
}

// ---------------------------------------------------------------- per-layer driver

struct LayerPtrs {
  int* idx; float *p, *q, *zmx, *zmn, *stats, *D;
  u16 *Wh, *Wl, *Wh1, *Wl1;
};

template<int Cin, int C>
static void run_edgeconv(const float* xin,
                         const float* W1, const float* b1, const float* g1, const float* e1,
                         const float* W2, const float* b2, const float* g2, const float* e2,
                         float* hout, const LayerPtrs& L, hipStream_t stream) {
  float* s1 = L.stats;
  float* ss1 = L.stats + 256;
  float* s2 = L.stats + 512;
  float* ss2 = L.stats + 768;
  float* sc1 = L.stats + 1024;
  float* sh1 = L.stats + 1280;

  (void)hipMemsetAsync(L.stats, 0, 4 * 256 * sizeof(float), stream);
  dist_kernel<Cin><<<dim3(BB * 4), dim3(256), 0, stream>>>(xin, L.D);
  select_kernel<<<dim3(MNODE / 4), dim3(256), 0, stream>>>(L.D, L.idx);
  if constexpr (Cin >= 16) {
    pack_w1<Cin, 2 * C><<<dim3((Cin * 2 * C + 255) / 256), dim3(256), 0, stream>>>(W1, L.Wh1, L.Wl1);
    node_gemm_mfma<Cin, 2 * C><<<dim3(MNODE / 32), dim3(256), 0, stream>>>(xin, L.Wh1, L.Wl1, L.p, L.q);
  } else {
    node_gemm<<<dim3(MNODE / 8), dim3(C), 0, stream>>>(xin, W1, L.p, L.q, Cin, C);
  }
  pack_w2<C><<<dim3((C * C + 255) / 256), dim3(256), 0, stream>>>(W2, L.Wh, L.Wl);
  edge_stats1v<C><<<dim3(MNODE / 4), dim3(256), 0, stream>>>(L.p, L.q, b1, L.idx, s1, ss1);
  bn_params<<<dim3(1), dim3(C), 0, stream>>>(s1, ss1, g1, e1, b1, (float)MEDGE, sc1, sh1);
  constexpr int NSLICE = (C == 256) ? 2 : 1;
  edge_gemm2_v6<C><<<dim3((MNODE / 8) * NSLICE), dim3(512), 0, stream>>>(
      L.p, L.q, L.idx, sc1, sh1, L.Wh, L.Wl, b2, L.zmx, L.zmn, s2, ss2);
  finalize2_kernel<<<dim3(MNODE * C / 256), dim3(256), 0, stream>>>(
      L.zmx, L.zmn, s2, ss2, g2, e2, hout, C - 1);
}

// ---------------------------------------------------------------- launch

extern "C" void kernel_launch(void* const* d_in, const int* in_sizes, int n_in,
                              void* d_out, int out_size, void* d_ws, size_t ws_size,
                              hipStream_t stream) {
  const float* x   = (const float*)d_in[0];
  const float* w11 = (const float*)d_in[1];
  const float* b11 = (const float*)d_in[2];
  const float* g11 = (const float*)d_in[3];
  const float* e11 = (const float*)d_in[4];
  const float* w12 = (const float*)d_in[5];
  const float* b12 = (const float*)d_in[6];
  const float* g12 = (const float*)d_in[7];
  const float* e12 = (const float*)d_in[8];
  const float* w21 = (const float*)d_in[9];
  const float* b21 = (const float*)d_in[10];
  const float* g21 = (const float*)d_in[11];
  const float* e21 = (const float*)d_in[12];
  const float* w22 = (const float*)d_in[13];
  const float* b22 = (const float*)d_in[14];
  const float* g22 = (const float*)d_in[15];
  const float* e22 = (const float*)d_in[16];
  const float* w31 = (const float*)d_in[17];
  const float* b31 = (const float*)d_in[18];
  const float* g31 = (const float*)d_in[19];
  const float* e31 = (const float*)d_in[20];
  const float* w32 = (const float*)d_in[21];
  const float* b32 = (const float*)d_in[22];
  const float* g32 = (const float*)d_in[23];
  const float* e32 = (const float*)d_in[24];
  const float* fw1 = (const float*)d_in[25];
  const float* fb1 = (const float*)d_in[26];
  const float* fg1 = (const float*)d_in[27];
  const float* fe1 = (const float*)d_in[28];
  const float* fw2 = (const float*)d_in[29];
  const float* fb2 = (const float*)d_in[30];
  const float* fg2 = (const float*)d_in[31];
  const float* fe2 = (const float*)d_in[32];
  const float* fw3 = (const float*)d_in[33];
  const float* fb3 = (const float*)d_in[34];

  char* wsb = (char*)d_ws;
  size_t o = 0;
  auto alloc = [&](size_t bytes) -> void* {
    void* r = wsb + o;
    o += (bytes + 255) & ~(size_t)255;
    return r;
  };
  LayerPtrs L;
  L.idx   = (int*)  alloc((size_t)MNODE * KK * sizeof(int));
  L.p     = (float*)alloc((size_t)MNODE * 256 * sizeof(float));
  L.q     = (float*)alloc((size_t)MNODE * 256 * sizeof(float));
  L.zmx   = (float*)alloc((size_t)MNODE * 256 * sizeof(float));
  L.zmn   = (float*)alloc((size_t)MNODE * 256 * sizeof(float));
  L.stats = (float*)alloc(8 * 256 * sizeof(float));
  L.D     = (float*)alloc((size_t)MNODE * NN * sizeof(float));
  L.Wh    = (u16*)  alloc((size_t)256 * 256 * sizeof(u16));
  L.Wl    = (u16*)  alloc((size_t)256 * 256 * sizeof(u16));
  L.Wh1   = (u16*)  alloc((size_t)128 * 512 * sizeof(u16));
  L.Wl1   = (u16*)  alloc((size_t)128 * 512 * sizeof(u16));
  float* h1buf   = (float*)alloc((size_t)MNODE * 64 * sizeof(float));
  float* h2buf   = (float*)alloc((size_t)MNODE * 128 * sizeof(float));
  float* h3buf   = (float*)alloc((size_t)MNODE * 256 * sizeof(float));
  float* pooled  = (float*)alloc(128 * 512 * sizeof(float));
  float* t1raw   = (float*)alloc(128 * 256 * sizeof(float));
  float* t2raw   = (float*)alloc(128 * 128 * sizeof(float));
  float* fcstats = (float*)alloc(8 * 256 * sizeof(float));

  float* fs  = fcstats;
  float* fss = fcstats + 256;
  float* gs  = fcstats + 512;
  float* gss = fcstats + 768;

  (void)hipMemsetAsync(fcstats, 0, 4 * 256 * sizeof(float), stream);

  run_edgeconv<6,   64 >(x,     w11, b11, g11, e11, w12, b12, g12, e12, h1buf, L, stream);
  run_edgeconv<64,  128>(h1buf, w21, b21, g21, e21, w22, b22, g22, e22, h2buf, L, stream);
  run_edgeconv<128, 256>(h2buf, w31, b31, g31, e31, w32, b32, g32, e32, h3buf, L, stream);

  pool_kernel<<<dim3(BB), dim3(256), 0, stream>>>(h3buf, pooled);
  fc1_fused<<<dim3(BB), dim3(256), 0, stream>>>(pooled, fw1, fb1, t1raw, fs, fss);
  fc2_fused<<<dim3(BB), dim3(256), 0, stream>>>(t1raw, fs, fss, fg1, fe1, fw2, fb2, t2raw, gs, gss);
  fc3_fused<<<dim3(1), dim3(256), 0, stream>>>(t2raw, gs, gss, fg2, fe2, fw3, fb3, (float*)d_out);
}

// Round 10
// 1206.700 us; speedup vs baseline: 1.1123x; 1.1123x over previous
//
#include <hip/hip_runtime.h>
#include <math.h>

#define BB 128
#define NN 128
#define KK 16
#define MEDGE (BB*NN*KK)   // 262144 edges
#define MNODE (BB*NN)      // 16384 nodes

typedef __bf16 bf16x8 __attribute__((ext_vector_type(8)));
typedef float  floatx4 __attribute__((ext_vector_type(4)));
typedef float  floatx16 __attribute__((ext_vector_type(16)));
typedef unsigned short u16;
typedef u16 ushort8_alias __attribute__((ext_vector_type(8)));

// ---------------------------------------------------------------- utilities

__device__ __forceinline__ unsigned ord32(float f) {
  unsigned u = __float_as_uint(f);
  return (u & 0x80000000u) ? ~u : (u | 0x80000000u);
}

__device__ __forceinline__ unsigned long long shfl_xor_u64(unsigned long long v, int m) {
  unsigned lo = (unsigned)(v & 0xffffffffull);
  unsigned hi = (unsigned)(v >> 32);
  lo = __shfl_xor(lo, m, 64);
  hi = __shfl_xor(hi, m, 64);
  return (((unsigned long long)hi) << 32) | (unsigned long long)lo;
}

__device__ __forceinline__ u16 bf16_rne_bits(float x) {
  unsigned u = __float_as_uint(x);
  return (u16)((u + 0x7FFF + ((u >> 16) & 1)) >> 16);
}

// ---------------------------------------------------------------- kNN: distances
template<int C>
__global__ __launch_bounds__(256) void dist_kernel(const float* __restrict__ x,
                                                   float* __restrict__ D) {
  constexpr int CH = (C < 64) ? C : 64;
  constexpr int NP = C / CH;
  constexpr int S = CH + 2;
  __shared__ float xs[NN * S];
  __shared__ float sq[NN];
  int b = blockIdx.x >> 2, qr = blockIdx.x & 3;
  const float* xb = x + (size_t)b * NN * C;
  int rg = threadIdx.x >> 5, cg = threadIdx.x & 31;
  int r0 = qr * 32 + rg * 4;

  float acc[4][4];
#pragma unroll
  for (int i = 0; i < 4; ++i)
#pragma unroll
    for (int j = 0; j < 4; ++j) acc[i][j] = 0.f;
  float sqacc = 0.f;

  for (int ps = 0; ps < NP; ++ps) {
    int c0 = ps * CH;
    __syncthreads();
    for (int t = threadIdx.x; t < NN * CH; t += 256) {
      int row = t / CH, c = t - row * CH;
      xs[row * S + c] = xb[(size_t)row * C + c0 + c];
    }
    __syncthreads();
    if (threadIdx.x < NN) {
      const float* xr = xs + threadIdx.x * S;
      float s = sqacc;
      for (int c = 0; c < CH; ++c) s = fmaf(xr[c], xr[c], s);
      sqacc = s;
    }
    for (int c = 0; c < CH; c += 2) {
      float2 av[4], bv[4];
#pragma unroll
      for (int i = 0; i < 4; ++i) av[i] = *(const float2*)&xs[(r0 + i) * S + c];
#pragma unroll
      for (int j = 0; j < 4; ++j) bv[j] = *(const float2*)&xs[(cg + 32 * j) * S + c];
#pragma unroll
      for (int i = 0; i < 4; ++i)
#pragma unroll
        for (int j = 0; j < 4; ++j) {
          acc[i][j] = fmaf(av[i].x, bv[j].x, acc[i][j]);
          acc[i][j] = fmaf(av[i].y, bv[j].y, acc[i][j]);
        }
    }
  }
  __syncthreads();
  if (threadIdx.x < NN) sq[threadIdx.x] = sqacc;
  __syncthreads();
#pragma unroll
  for (int i = 0; i < 4; ++i) {
    float sn = sq[r0 + i];
#pragma unroll
    for (int j = 0; j < 4; ++j) {
      int m = cg + 32 * j;
      D[((size_t)(b * NN + r0 + i)) * NN + m] = sn - 2.f * acc[i][j] + sq[m];
    }
  }
}

// ---------------------------------------------------------------- kNN: selection
__global__ __launch_bounds__(256) void select_kernel(const float* __restrict__ D,
                                                     int* __restrict__ idx) {
  int lane = threadIdx.x & 63, wv = threadIdx.x >> 6;
  int nd = blockIdx.x * 4 + wv;
  const float* dr = D + (size_t)nd * NN;
  unsigned long long key[2];
  key[0] = (((unsigned long long)ord32(dr[lane])) << 32) | (unsigned)lane;
  key[1] = (((unsigned long long)ord32(dr[lane + 64])) << 32) | (unsigned)(lane + 64);
  int* out = idx + (size_t)nd * KK;
  for (int r = 0; r < KK; ++r) {
    unsigned long long mk = key[0] < key[1] ? key[0] : key[1];
#pragma unroll
    for (int off = 32; off > 0; off >>= 1) {
      unsigned long long o = shfl_xor_u64(mk, off);
      if (o < mk) mk = o;
    }
    int wm = (int)(mk & 0xffffffffu);
    if (lane == 0) out[r] = wm;
    if ((wm & 63) == lane) key[wm >> 6] = ~0ull;
  }
}

// ---------------------------------------------------------------- node GEMM (scalar, layer-1 only)
__global__ __launch_bounds__(256) void node_gemm(const float* __restrict__ x,
                                                 const float* __restrict__ W,
                                                 float* __restrict__ p, float* __restrict__ q,
                                                 int Cin, int Cout) {
  int c = threadIdx.x;
  __shared__ float xr[128];
  for (int r = 0; r < 8; ++r) {
    int row = blockIdx.x * 8 + r;
    __syncthreads();
    for (int i = c; i < Cin; i += blockDim.x) xr[i] = x[(size_t)row * Cin + i];
    __syncthreads();
    float a = 0.f, qv = 0.f;
    for (int i = 0; i < Cin; ++i) {
      float xv = xr[i];
      a  = fmaf(xv, W[i * Cout + c], a);
      qv = fmaf(xv, W[(Cin + i) * Cout + c], qv);
    }
    p[(size_t)row * Cout + c] = a - qv;
    q[(size_t)row * Cout + c] = qv;
  }
}

// ---------------------------------------------------------------- W1 packing (32x32x16, node GEMM)
template<int K, int N>
__global__ __launch_bounds__(256) void pack_w1(const float* __restrict__ W1,
                                               u16* __restrict__ Wh, u16* __restrict__ Wl) {
  int t = blockIdx.x * 256 + threadIdx.x;
  if (t >= K * N) return;
  constexpr int C = N / 2;
  constexpr int NT2 = N / 32;
  int j = t & 7, lane = (t >> 3) & 63, tile = t >> 9;
  int nt = tile % NT2, kt = tile / NT2;
  int row = kt * 16 + (lane >> 5) * 8 + j;
  int col = nt * 32 + (lane & 31);
  float w;
  if (col < C) w = W1[row * C + col] - W1[(K + row) * C + col];
  else         w = W1[(K + row) * C + (col - C)];
  u16 h = bf16_rne_bits(w);
  float hf = __uint_as_float(((unsigned)h) << 16);
  Wh[t] = h;
  Wl[t] = bf16_rne_bits(w - hf);
}

// ---------------------------------------------------------------- MFMA node GEMM (layers 2,3)
template<int K, int N>
__global__ __launch_bounds__(256, 2) void node_gemm_mfma(
    const float* __restrict__ x, const u16* __restrict__ Wh, const u16* __restrict__ Wl,
    float* __restrict__ p, float* __restrict__ q) {
  constexpr int C = N / 2, KT = K / 16, NT2 = N / 32, NTQ = NT2 / 4;
  constexpr int CHK = NT2 * 64;
  __shared__ __align__(16) u16 Bst[2][2][CHK * 8];
  int tid = threadIdx.x, lane = tid & 63, wv = tid >> 6;
  int m = lane & 31, lh = lane >> 5;
  int rowBase = blockIdx.x * 32;
  const float* xr = x + (size_t)(rowBase + m) * K;

  floatx16 acc[NTQ];
#pragma unroll
  for (int nt = 0; nt < NTQ; ++nt)
#pragma unroll
    for (int r = 0; r < 16; ++r) acc[nt][r] = 0.f;

  float4 fxa[2], fxb[2];
  auto loadX = [&](int kt, int buf) {
    int c0 = kt * 16 + lh * 8;
    fxa[buf] = *(const float4*)(xr + c0);
    fxb[buf] = *(const float4*)(xr + c0 + 4);
  };
  auto stage = [&](int kt, int buf) {
    const ushort8_alias* srcH = (const ushort8_alias*)Wh + (size_t)kt * CHK;
    const ushort8_alias* srcL = (const ushort8_alias*)Wl + (size_t)kt * CHK;
    ushort8_alias* dH = (ushort8_alias*)Bst[buf][0];
    ushort8_alias* dL = (ushort8_alias*)Bst[buf][1];
    for (int i = tid; i < CHK; i += 256) { dH[i] = srcH[i]; dL[i] = srcL[i]; }
  };
  loadX(0, 0);
  stage(0, 0);
  __syncthreads();

#pragma unroll 2
  for (int kt = 0; kt < KT; ++kt) {
    int buf = kt & 1;
    if (kt + 1 < KT) { loadX(kt + 1, buf ^ 1); stage(kt + 1, buf ^ 1); }
    float hv[8];
    hv[0] = fxa[buf].x; hv[1] = fxa[buf].y; hv[2] = fxa[buf].z; hv[3] = fxa[buf].w;
    hv[4] = fxb[buf].x; hv[5] = fxb[buf].y; hv[6] = fxb[buf].z; hv[7] = fxb[buf].w;
    bf16x8 ah, al;
#pragma unroll
    for (int t = 0; t < 8; ++t) {
      __bf16 hb = (__bf16)hv[t];
      ah[t] = hb;
      al[t] = (__bf16)(hv[t] - (float)hb);
    }
#pragma unroll
    for (int nt = 0; nt < NTQ; ++nt) {
      int e = (wv * NTQ + nt) * 64 + lane;
      bf16x8 bh = __builtin_bit_cast(bf16x8, ((const ushort8_alias*)Bst[buf][0])[e]);
      bf16x8 bl = __builtin_bit_cast(bf16x8, ((const ushort8_alias*)Bst[buf][1])[e]);
      acc[nt] = __builtin_amdgcn_mfma_f32_32x32x16_bf16(ah, bh, acc[nt], 0, 0, 0);
      acc[nt] = __builtin_amdgcn_mfma_f32_32x32x16_bf16(al, bh, acc[nt], 0, 0, 0);
      acc[nt] = __builtin_amdgcn_mfma_f32_32x32x16_bf16(ah, bl, acc[nt], 0, 0, 0);
    }
    __syncthreads();
  }

#pragma unroll
  for (int nt = 0; nt < NTQ; ++nt) {
    int n = (wv * NTQ + nt) * 32 + m;
    float* dst = (n < C) ? p : q;
    int col = (n < C) ? n : n - C;
#pragma unroll
    for (int r = 0; r < 16; ++r) {
      int row = rowBase + (r & 3) + 8 * (r >> 2) + 4 * lh;
      dst[(size_t)row * C + col] = acc[nt][r];
    }
  }
}

// ---------------------------------------------------------------- BN1 stats (vectorized)
template<int C>
__global__ __launch_bounds__(256) void edge_stats1v(const float* __restrict__ p,
                                                    const float* __restrict__ q,
                                                    const float* __restrict__ b1,
                                                    const int* __restrict__ idx,
                                                    float* __restrict__ s1,
                                                    float* __restrict__ ss1) {
  constexpr int G = C / 4;
  constexpr int KL = 64 / G;
  int tid = threadIdx.x, lane = tid & 63, wv = tid >> 6;
  int nd = blockIdx.x * 4 + wv;
  int b = nd >> 7;
  int g = lane % G, kl = lane / G;

  __shared__ float sS[C], sSS[C];
  if (tid < C) { sS[tid] = 0.f; sSS[tid] = 0.f; }
  __syncthreads();

  const float* pr = p + (size_t)nd * C;
  float4 pv = *(const float4*)(pr + g * 4);
  float4 bv = *(const float4*)(b1 + g * 4);
  pv.x += bv.x; pv.y += bv.y; pv.z += bv.z; pv.w += bv.w;
  float4 s = {0, 0, 0, 0}, ss = {0, 0, 0, 0};
  const int* id = idx + (size_t)nd * KK;
#pragma unroll
  for (int k0 = 0; k0 < KK; k0 += KL) {
    int j = id[k0 + kl];
    float4 q4 = *(const float4*)(q + (size_t)(b * NN + j) * C + g * 4);
    float y;
    y = pv.x + q4.x; s.x += y; ss.x = fmaf(y, y, ss.x);
    y = pv.y + q4.y; s.y += y; ss.y = fmaf(y, y, ss.y);
    y = pv.z + q4.z; s.z += y; ss.z = fmaf(y, y, ss.z);
    y = pv.w + q4.w; s.w += y; ss.w = fmaf(y, y, ss.w);
  }
#pragma unroll
  for (int off = G; off < 64; off <<= 1) {
    s.x += __shfl_xor(s.x, off); ss.x += __shfl_xor(ss.x, off);
    s.y += __shfl_xor(s.y, off); ss.y += __shfl_xor(ss.y, off);
    s.z += __shfl_xor(s.z, off); ss.z += __shfl_xor(ss.z, off);
    s.w += __shfl_xor(s.w, off); ss.w += __shfl_xor(ss.w, off);
  }
  if (kl == 0) {
    atomicAdd(&sS[g * 4 + 0], s.x); atomicAdd(&sSS[g * 4 + 0], ss.x);
    atomicAdd(&sS[g * 4 + 1], s.y); atomicAdd(&sSS[g * 4 + 1], ss.y);
    atomicAdd(&sS[g * 4 + 2], s.z); atomicAdd(&sSS[g * 4 + 2], ss.z);
    atomicAdd(&sS[g * 4 + 3], s.w); atomicAdd(&sSS[g * 4 + 3], ss.w);
  }
  __syncthreads();
  if (tid < C) {
    atomicAdd(&s1[tid], sS[tid]);
    atomicAdd(&ss1[tid], sSS[tid]);
  }
}

// ---------------------------------------------------------------- BN params (BN1 only)
__global__ void bn_params(const float* __restrict__ s, const float* __restrict__ ss,
                          const float* __restrict__ g, const float* __restrict__ beta,
                          const float* __restrict__ bias,
                          float M, float* __restrict__ scale, float* __restrict__ shift) {
  int c = threadIdx.x;
  float mean = s[c] / M;
  float var = ss[c] / M - mean * mean;
  if (var < 0.f) var = 0.f;
  float sc = g[c] * rsqrtf(var + 1e-5f);
  scale[c] = sc;
  float sh = beta[c] - mean * sc;
  if (bias) sh += sc * bias[c];
  shift[c] = sh;
}

// ---------------------------------------------------------------- W2 packing (16x16x32)
// B operand of v_mfma_f32_16x16x32_bf16: B[k][n], n = lane&15, k = (lane>>4)*8+j.
// Flat ushort8 chunk: (kt*NT + nt)*64 + lane, element j.
template<int C>
__global__ __launch_bounds__(256) void pack_w2(const float* __restrict__ W,
                                               u16* __restrict__ Wh, u16* __restrict__ Wl) {
  int t = blockIdx.x * 256 + threadIdx.x;
  if (t >= C * C) return;
  constexpr int NT = C / 16;
  int j = t & 7, lane = (t >> 3) & 63, tile = t >> 9;
  int nt = tile % NT, kt = tile / NT;
  int row = kt * 32 + (lane >> 4) * 8 + j;
  int col = nt * 16 + (lane & 15);
  float w = W[row * C + col];
  u16 h = bf16_rne_bits(w);
  float hf = __uint_as_float(((unsigned)h) << 16);
  Wh[t] = h;
  Wl[t] = bf16_rne_bits(w - hf);
}

// ---------------------------------------------------------------- MFMA edge GEMM2 v7
// 16x16x32. Block = 4 waves = 4 nodes x one N-slice (<=128 cols).
// Per wave: one node (M=16 neighbors), A hi/lo REGISTER-resident (all indices
// compile-time: every loop over KT/NWIN is #pragma unroll — this is what v6
// got wrong, dynamic Ah[kt] indexing spilled to scratch).
// B staged in a 32 KB LDS window (CK=2 k-tiles x NTS n-tiles x hi/lo), 3-4
// blocks/CU so barrier stalls overlap across blocks.
// Epilogue: C/D row=(lane>>4)*4+reg = neighbor, col=lane&15 = channel.
template<int C>
__global__ __launch_bounds__(256, (C > 128) ? 3 : 4) void edge_gemm2_v7(
    const float* __restrict__ p, const float* __restrict__ q,
    const int* __restrict__ idx,
    const float* __restrict__ sc1, const float* __restrict__ sh1,  // bias1 folded into sh1
    const u16* __restrict__ Wh, const u16* __restrict__ Wl,
    const float* __restrict__ b2,
    float* __restrict__ zmax, float* __restrict__ zmin,
    float* __restrict__ s2, float* __restrict__ ss2) {
  constexpr int KT = C / 32;                 // k-tiles (K=32 each): 8,4,2
  constexpr int NT = C / 16;                 // global n-tiles
  constexpr int NSLICE = (C > 128) ? 2 : 1;
  constexpr int NCOL = C / NSLICE;           // 128,128,64
  constexpr int NTS = NCOL / 16;             // n-tiles per slice: 8,8,4
  constexpr int CK = 2;                      // k-tiles per LDS window
  constexpr int NWIN = KT / CK;              // 4,2,1
  constexpr int CCH = CK * NTS * 2 * 64;     // ushort8 chunks per window
  __shared__ __align__(16) u16 Bst[CCH * 8];

  int tid = threadIdx.x, lane = tid & 63, wv = tid >> 6;
  int r = lane & 15, kseg = lane >> 4;

  int bid = blockIdx.x;
  int g = bid / NSLICE, slice = bid % NSLICE;
  // XCD swizzle: groups of a batch share an XCD for q-slab L2 locality.
  int u = g >> 3, xcd = g & 7;
  int b = xcd + 8 * (u >> 5);
  int nodeBase = b * NN + (u & 31) * 4;
  int nd = nodeBase + wv;

  int j = idx[(size_t)nd * KK + r];
  const float* pr = p + (size_t)nd * C;
  const float* qr = q + (size_t)(b * NN + j) * C;

  // ---- build A (hi/lo bf16 split) into registers, once; all indices constant
  bf16x8 Ah[KT], Al[KT];
#pragma unroll
  for (int kt = 0; kt < KT; ++kt) {
    int c0 = kt * 32 + kseg * 8;
    float4 pa = *(const float4*)(pr + c0);
    float4 pb = *(const float4*)(pr + c0 + 4);
    float4 qa = *(const float4*)(qr + c0);
    float4 qb = *(const float4*)(qr + c0 + 4);
    float4 sa = *(const float4*)(sc1 + c0);
    float4 sb = *(const float4*)(sc1 + c0 + 4);
    float4 ta = *(const float4*)(sh1 + c0);
    float4 tb = *(const float4*)(sh1 + c0 + 4);
    float hv[8];
    hv[0] = fmaxf(fmaf(pa.x + qa.x, sa.x, ta.x), 0.f);
    hv[1] = fmaxf(fmaf(pa.y + qa.y, sa.y, ta.y), 0.f);
    hv[2] = fmaxf(fmaf(pa.z + qa.z, sa.z, ta.z), 0.f);
    hv[3] = fmaxf(fmaf(pa.w + qa.w, sa.w, ta.w), 0.f);
    hv[4] = fmaxf(fmaf(pb.x + qb.x, sb.x, tb.x), 0.f);
    hv[5] = fmaxf(fmaf(pb.y + qb.y, sb.y, tb.y), 0.f);
    hv[6] = fmaxf(fmaf(pb.z + qb.z, sb.z, tb.z), 0.f);
    hv[7] = fmaxf(fmaf(pb.w + qb.w, sb.w, tb.w), 0.f);
#pragma unroll
    for (int t = 0; t < 8; ++t) {
      __bf16 hb = (__bf16)hv[t];
      Ah[kt][t] = hb;
      Al[kt][t] = (__bf16)(hv[t] - (float)hb);
    }
  }

  floatx4 acc[NTS];
#pragma unroll
  for (int nt = 0; nt < NTS; ++nt) {
    float bv = b2[slice * NCOL + nt * 16 + r];
    acc[nt] = {bv, bv, bv, bv};
  }

  // ---- K-loop over LDS windows (fully unrolled: Ah indices stay constant)
#pragma unroll
  for (int w = 0; w < NWIN; ++w) {
    __syncthreads();
    for (int i = tid; i < CCH; i += 256) {
      int c = i & 63, h = (i >> 6) & 1, rest = i >> 7;   // rest = kk*NTS+nt
      int nt = rest % NTS, kk = rest / NTS;
      const ushort8_alias* src = h ? (const ushort8_alias*)Wl : (const ushort8_alias*)Wh;
      ((ushort8_alias*)Bst)[i] = src[((w * CK + kk) * NT + slice * NTS + nt) * 64 + c];
    }
    __syncthreads();
#pragma unroll
    for (int kk = 0; kk < CK; ++kk) {
#pragma unroll
      for (int nt = 0; nt < NTS; ++nt) {
        int base = (kk * NTS + nt) * 128 + lane;
        bf16x8 bh = __builtin_bit_cast(bf16x8, ((const ushort8_alias*)Bst)[base]);
        bf16x8 bl = __builtin_bit_cast(bf16x8, ((const ushort8_alias*)Bst)[base + 64]);
        acc[nt] = __builtin_amdgcn_mfma_f32_16x16x32_bf16(Ah[w * CK + kk], bh, acc[nt], 0, 0, 0);
        acc[nt] = __builtin_amdgcn_mfma_f32_16x16x32_bf16(Al[w * CK + kk], bh, acc[nt], 0, 0, 0);
        acc[nt] = __builtin_amdgcn_mfma_f32_16x16x32_bf16(Ah[w * CK + kk], bl, acc[nt], 0, 0, 0);
      }
    }
  }

  // ---- epilogue (reuse LDS for stats)
  __syncthreads();
  float* sS = (float*)Bst;
  float* sSS = sS + NCOL;
  if (tid < NCOL) { sS[tid] = 0.f; sSS[tid] = 0.f; }
  __syncthreads();

#pragma unroll
  for (int nt = 0; nt < NTS; ++nt) {
    float s = 0.f, ss = 0.f, mx = -INFINITY, mn = INFINITY;
#pragma unroll
    for (int gi = 0; gi < 4; ++gi) {
      float z = acc[nt][gi];
      s += z; ss = fmaf(z, z, ss);
      mx = fmaxf(mx, z); mn = fminf(mn, z);
    }
    mx = fmaxf(mx, __shfl_xor(mx, 16)); mn = fminf(mn, __shfl_xor(mn, 16));
    s += __shfl_xor(s, 16); ss += __shfl_xor(ss, 16);
    mx = fmaxf(mx, __shfl_xor(mx, 32)); mn = fminf(mn, __shfl_xor(mn, 32));
    s += __shfl_xor(s, 32); ss += __shfl_xor(ss, 32);
    if (kseg == 0) {
      int colL = nt * 16 + r;
      int col = slice * NCOL + colL;
      zmax[(size_t)nd * C + col] = mx;
      zmin[(size_t)nd * C + col] = mn;
      atomicAdd(&sS[colL], s);
      atomicAdd(&sSS[colL], ss);
    }
  }
  __syncthreads();
  if (tid < NCOL) {
    atomicAdd(&s2[slice * NCOL + tid], sS[tid]);
    atomicAdd(&ss2[slice * NCOL + tid], sSS[tid]);
  }
}

// ---------------------------------------------------------------- finalize (BN2 params folded in)
__global__ __launch_bounds__(256) void finalize2_kernel(const float* __restrict__ zmax,
                                                        const float* __restrict__ zmin,
                                                        const float* __restrict__ s2,
                                                        const float* __restrict__ ss2,
                                                        const float* __restrict__ g2,
                                                        const float* __restrict__ e2,
                                                        float* __restrict__ out, int Cmask) {
  int t = blockIdx.x * 256 + threadIdx.x;
  int c = t & Cmask;
  float mean = s2[c] / (float)MEDGE;
  float var = ss2[c] / (float)MEDGE - mean * mean;
  if (var < 0.f) var = 0.f;
  float scl = g2[c] * rsqrtf(var + 1e-5f);
  float shf = e2[c] - mean * scl;
  float v = (scl >= 0.f) ? zmax[t] : zmin[t];
  out[t] = fmaxf(fmaf(v, scl, shf), 0.f);
}

// ---------------------------------------------------------------- pooling
__global__ __launch_bounds__(256) void pool_kernel(const float* __restrict__ h,
                                                   float* __restrict__ pooled) {
  int b = blockIdx.x, c = threadIdx.x;
  float s = 0.f, mx = -INFINITY;
  for (int n = 0; n < NN; ++n) {
    float v = h[(size_t)(b * NN + n) * 256 + c];
    s += v;
    mx = fmaxf(mx, v);
  }
  pooled[b * 512 + c] = s * (1.f / 128.f);
  pooled[b * 512 + 256 + c] = mx;
}

// ---------------------------------------------------------------- FC tail
__global__ __launch_bounds__(256) void fc1_fused(const float* __restrict__ pooled,
                                                 const float* __restrict__ W,
                                                 const float* __restrict__ bias,
                                                 float* __restrict__ t1raw,
                                                 float* __restrict__ fs, float* __restrict__ fss) {
  int b = blockIdx.x, c = threadIdx.x;
  __shared__ float row[512];
  row[c] = pooled[b * 512 + c];
  row[c + 256] = pooled[b * 512 + 256 + c];
  __syncthreads();
  float acc = bias[c];
  for (int i = 0; i < 512; ++i) acc = fmaf(row[i], W[i * 256 + c], acc);
  t1raw[b * 256 + c] = acc;
  atomicAdd(&fs[c], acc);
  atomicAdd(&fss[c], acc * acc);
}

__global__ __launch_bounds__(256) void fc2_fused(const float* __restrict__ t1raw,
                                                 const float* __restrict__ fs,
                                                 const float* __restrict__ fss,
                                                 const float* __restrict__ g1,
                                                 const float* __restrict__ e1,
                                                 const float* __restrict__ W,
                                                 const float* __restrict__ bias,
                                                 float* __restrict__ t2raw,
                                                 float* __restrict__ gs, float* __restrict__ gss) {
  int b = blockIdx.x, c = threadIdx.x;
  __shared__ float row[256];
  {
    float mean = fs[c] / 128.f;
    float var = fss[c] / 128.f - mean * mean;
    if (var < 0.f) var = 0.f;
    float scl = g1[c] * rsqrtf(var + 1e-5f);
    float shf = e1[c] - mean * scl;
    row[c] = fmaxf(fmaf(t1raw[b * 256 + c], scl, shf), 0.f);
  }
  __syncthreads();
  if (c < 128) {
    float acc = bias[c];
    for (int i = 0; i < 256; ++i) acc = fmaf(row[i], W[i * 128 + c], acc);
    t2raw[b * 128 + c] = acc;
    atomicAdd(&gs[c], acc);
    atomicAdd(&gss[c], acc * acc);
  }
}

__global__ __launch_bounds__(256) void fc3_fused(const float* __restrict__ t2raw,
                                                 const float* __restrict__ gs,
                                                 const float* __restrict__ gss,
                                                 const float* __restrict__ g2,
                                                 const float* __restrict__ e2,
                                                 const float* __restrict__ W,
                                                 const float* __restrict__ bias,
                                                 float* __restrict__ out) {
  __shared__ float row[128 * 2];
  int t = threadIdx.x;
  if (t < 128) {
    float mean = gs[t] / 128.f;
    float var = gss[t] / 128.f - mean * mean;
    if (var < 0.f) var = 0.f;
    float scl = g2[t] * rsqrtf(var + 1e-5f);
    row[t] = scl;
    row[128 + t] = e2[t] - mean * scl;
  }
  __syncthreads();
  int b = t >> 1, jj = t & 1;
  float acc = bias[jj];
  for (int r = 0; r < 128; ++r) {
    float v = fmaxf(fmaf(t2raw[b * 128 + r], row[r], row[128 + r]), 0.f);
    acc = fmaf(v, W[r * 2 + jj], acc);
  }
  out[t] = acc;
}

// ---------------------------------------------------------------- per-layer driver

struct LayerPtrs {
  int* idx; float *p, *q, *zmx, *zmn, *stats, *D;
  u16 *Wh, *Wl, *Wh1, *Wl1;
};

template<int Cin, int C>
static void run_edgeconv(const float* xin,
                         const float* W1, const float* b1, const float* g1, const float* e1,
                         const float* W2, const float* b2, const float* g2, const float* e2,
                         float* hout, const LayerPtrs& L, hipStream_t stream) {
  float* s1 = L.stats;
  float* ss1 = L.stats + 256;
  float* s2 = L.stats + 512;
  float* ss2 = L.stats + 768;
  float* sc1 = L.stats + 1024;
  float* sh1 = L.stats + 1280;

  (void)hipMemsetAsync(L.stats, 0, 4 * 256 * sizeof(float), stream);
  dist_kernel<Cin><<<dim3(BB * 4), dim3(256), 0, stream>>>(xin, L.D);
  select_kernel<<<dim3(MNODE / 4), dim3(256), 0, stream>>>(L.D, L.idx);
  if constexpr (Cin >= 16) {
    pack_w1<Cin, 2 * C><<<dim3((Cin * 2 * C + 255) / 256), dim3(256), 0, stream>>>(W1, L.Wh1, L.Wl1);
    node_gemm_mfma<Cin, 2 * C><<<dim3(MNODE / 32), dim3(256), 0, stream>>>(xin, L.Wh1, L.Wl1, L.p, L.q);
  } else {
    node_gemm<<<dim3(MNODE / 8), dim3(C), 0, stream>>>(xin, W1, L.p, L.q, Cin, C);
  }
  pack_w2<C><<<dim3((C * C + 255) / 256), dim3(256), 0, stream>>>(W2, L.Wh, L.Wl);
  edge_stats1v<C><<<dim3(MNODE / 4), dim3(256), 0, stream>>>(L.p, L.q, b1, L.idx, s1, ss1);
  bn_params<<<dim3(1), dim3(C), 0, stream>>>(s1, ss1, g1, e1, b1, (float)MEDGE, sc1, sh1);
  constexpr int NSLICE = (C > 128) ? 2 : 1;
  edge_gemm2_v7<C><<<dim3((MNODE / 4) * NSLICE), dim3(256), 0, stream>>>(
      L.p, L.q, L.idx, sc1, sh1, L.Wh, L.Wl, b2, L.zmx, L.zmn, s2, ss2);
  finalize2_kernel<<<dim3(MNODE * C / 256), dim3(256), 0, stream>>>(
      L.zmx, L.zmn, s2, ss2, g2, e2, hout, C - 1);
}

// ---------------------------------------------------------------- launch

extern "C" void kernel_launch(void* const* d_in, const int* in_sizes, int n_in,
                              void* d_out, int out_size, void* d_ws, size_t ws_size,
                              hipStream_t stream) {
  const float* x   = (const float*)d_in[0];
  const float* w11 = (const float*)d_in[1];
  const float* b11 = (const float*)d_in[2];
  const float* g11 = (const float*)d_in[3];
  const float* e11 = (const float*)d_in[4];
  const float* w12 = (const float*)d_in[5];
  const float* b12 = (const float*)d_in[6];
  const float* g12 = (const float*)d_in[7];
  const float* e12 = (const float*)d_in[8];
  const float* w21 = (const float*)d_in[9];
  const float* b21 = (const float*)d_in[10];
  const float* g21 = (const float*)d_in[11];
  const float* e21 = (const float*)d_in[12];
  const float* w22 = (const float*)d_in[13];
  const float* b22 = (const float*)d_in[14];
  const float* g22 = (const float*)d_in[15];
  const float* e22 = (const float*)d_in[16];
  const float* w31 = (const float*)d_in[17];
  const float* b31 = (const float*)d_in[18];
  const float* g31 = (const float*)d_in[19];
  const float* e31 = (const float*)d_in[20];
  const float* w32 = (const float*)d_in[21];
  const float* b32 = (const float*)d_in[22];
  const float* g32 = (const float*)d_in[23];
  const float* e32 = (const float*)d_in[24];
  const float* fw1 = (const float*)d_in[25];
  const float* fb1 = (const float*)d_in[26];
  const float* fg1 = (const float*)d_in[27];
  const float* fe1 = (const float*)d_in[28];
  const float* fw2 = (const float*)d_in[29];
  const float* fb2 = (const float*)d_in[30];
  const float* fg2 = (const float*)d_in[31];
  const float* fe2 = (const float*)d_in[32];
  const float* fw3 = (const float*)d_in[33];
  const float* fb3 = (const float*)d_in[34];

  char* wsb = (char*)d_ws;
  size_t o = 0;
  auto alloc = [&](size_t bytes) -> void* {
    void* r = wsb + o;
    o += (bytes + 255) & ~(size_t)255;
    return r;
  };
  LayerPtrs L;
  L.idx   = (int*)  alloc((size_t)MNODE * KK * sizeof(int));
  L.p     = (float*)alloc((size_t)MNODE * 256 * sizeof(float));
  L.q     = (float*)alloc((size_t)MNODE * 256 * sizeof(float));
  L.zmx   = (float*)alloc((size_t)MNODE * 256 * sizeof(float));
  L.zmn   = (float*)alloc((size_t)MNODE * 256 * sizeof(float));
  L.stats = (float*)alloc(8 * 256 * sizeof(float));
  L.D     = (float*)alloc((size_t)MNODE * NN * sizeof(float));
  L.Wh    = (u16*)  alloc((size_t)256 * 256 * sizeof(u16));
  L.Wl    = (u16*)  alloc((size_t)256 * 256 * sizeof(u16));
  L.Wh1   = (u16*)  alloc((size_t)128 * 512 * sizeof(u16));
  L.Wl1   = (u16*)  alloc((size_t)128 * 512 * sizeof(u16));
  float* h1buf   = (float*)alloc((size_t)MNODE * 64 * sizeof(float));
  float* h2buf   = (float*)alloc((size_t)MNODE * 128 * sizeof(float));
  float* h3buf   = (float*)alloc((size_t)MNODE * 256 * sizeof(float));
  float* pooled  = (float*)alloc(128 * 512 * sizeof(float));
  float* t1raw   = (float*)alloc(128 * 256 * sizeof(float));
  float* t2raw   = (float*)alloc(128 * 128 * sizeof(float));
  float* fcstats = (float*)alloc(8 * 256 * sizeof(float));

  float* fs  = fcstats;
  float* fss = fcstats + 256;
  float* gs  = fcstats + 512;
  float* gss = fcstats + 768;

  (void)hipMemsetAsync(fcstats, 0, 4 * 256 * sizeof(float), stream);

  run_edgeconv<6,   64 >(x,     w11, b11, g11, e11, w12, b12, g12, e12, h1buf, L, stream);
  run_edgeconv<64,  128>(h1buf, w21, b21, g21, e21, w22, b22, g22, e22, h2buf, L, stream);
  run_edgeconv<128, 256>(h2buf, w31, b31, g31, e31, w32, b32, g32, e32, h3buf, L, stream);

  pool_kernel<<<dim3(BB), dim3(256), 0, stream>>>(h3buf, pooled);
  fc1_fused<<<dim3(BB), dim3(256), 0, stream>>>(pooled, fw1, fb1, t1raw, fs, fss);
  fc2_fused<<<dim3(BB), dim3(256), 0, stream>>>(t1raw, fs, fss, fg1, fe1, fw2, fb2, t2raw, gs, gss);
  fc3_fused<<<dim3(1), dim3(256), 0, stream>>>(t2raw, gs, gss, fg2, fe2, fw3, fb3, (float*)d_out);
}

// Round 11
// 1113.996 us; speedup vs baseline: 1.2048x; 1.0832x over previous
//
#include <hip/hip_runtime.h>
#include <math.h>

#define BB 128
#define NN 128
#define KK 16
#define MEDGE (BB*NN*KK)   // 262144 edges
#define MNODE (BB*NN)      // 16384 nodes

typedef __bf16 bf16x8 __attribute__((ext_vector_type(8)));
typedef float  floatx4 __attribute__((ext_vector_type(4)));
typedef float  floatx16 __attribute__((ext_vector_type(16)));
typedef unsigned short u16;
typedef u16 ushort8_alias __attribute__((ext_vector_type(8)));

// ---------------------------------------------------------------- utilities

__device__ __forceinline__ unsigned ord32(float f) {
  unsigned u = __float_as_uint(f);
  return (u & 0x80000000u) ? ~u : (u | 0x80000000u);
}

__device__ __forceinline__ unsigned long long shfl_xor_u64(unsigned long long v, int m) {
  unsigned lo = (unsigned)(v & 0xffffffffull);
  unsigned hi = (unsigned)(v >> 32);
  lo = __shfl_xor(lo, m, 64);
  hi = __shfl_xor(hi, m, 64);
  return (((unsigned long long)hi) << 32) | (unsigned long long)lo;
}

__device__ __forceinline__ u16 bf16_rne_bits(float x) {
  unsigned u = __float_as_uint(x);
  return (u16)((u + 0x7FFF + ((u >> 16) & 1)) >> 16);
}

// ---------------------------------------------------------------- kNN: distances
template<int C>
__global__ __launch_bounds__(256) void dist_kernel(const float* __restrict__ x,
                                                   float* __restrict__ D) {
  constexpr int CH = (C < 64) ? C : 64;
  constexpr int NP = C / CH;
  constexpr int S = CH + 2;
  __shared__ float xs[NN * S];
  __shared__ float sq[NN];
  int b = blockIdx.x >> 2, qr = blockIdx.x & 3;
  const float* xb = x + (size_t)b * NN * C;
  int rg = threadIdx.x >> 5, cg = threadIdx.x & 31;
  int r0 = qr * 32 + rg * 4;

  float acc[4][4];
#pragma unroll
  for (int i = 0; i < 4; ++i)
#pragma unroll
    for (int j = 0; j < 4; ++j) acc[i][j] = 0.f;
  float sqacc = 0.f;

  for (int ps = 0; ps < NP; ++ps) {
    int c0 = ps * CH;
    __syncthreads();
    for (int t = threadIdx.x; t < NN * CH; t += 256) {
      int row = t / CH, c = t - row * CH;
      xs[row * S + c] = xb[(size_t)row * C + c0 + c];
    }
    __syncthreads();
    if (threadIdx.x < NN) {
      const float* xr = xs + threadIdx.x * S;
      float s = sqacc;
      for (int c = 0; c < CH; ++c) s = fmaf(xr[c], xr[c], s);
      sqacc = s;
    }
    for (int c = 0; c < CH; c += 2) {
      float2 av[4], bv[4];
#pragma unroll
      for (int i = 0; i < 4; ++i) av[i] = *(const float2*)&xs[(r0 + i) * S + c];
#pragma unroll
      for (int j = 0; j < 4; ++j) bv[j] = *(const float2*)&xs[(cg + 32 * j) * S + c];
#pragma unroll
      for (int i = 0; i < 4; ++i)
#pragma unroll
        for (int j = 0; j < 4; ++j) {
          acc[i][j] = fmaf(av[i].x, bv[j].x, acc[i][j]);
          acc[i][j] = fmaf(av[i].y, bv[j].y, acc[i][j]);
        }
    }
  }
  __syncthreads();
  if (threadIdx.x < NN) sq[threadIdx.x] = sqacc;
  __syncthreads();
#pragma unroll
  for (int i = 0; i < 4; ++i) {
    float sn = sq[r0 + i];
#pragma unroll
    for (int j = 0; j < 4; ++j) {
      int m = cg + 32 * j;
      D[((size_t)(b * NN + r0 + i)) * NN + m] = sn - 2.f * acc[i][j] + sq[m];
    }
  }
}

// ---------------------------------------------------------------- kNN: selection
__global__ __launch_bounds__(256) void select_kernel(const float* __restrict__ D,
                                                     int* __restrict__ idx) {
  int lane = threadIdx.x & 63, wv = threadIdx.x >> 6;
  int nd = blockIdx.x * 4 + wv;
  const float* dr = D + (size_t)nd * NN;
  unsigned long long key[2];
  key[0] = (((unsigned long long)ord32(dr[lane])) << 32) | (unsigned)lane;
  key[1] = (((unsigned long long)ord32(dr[lane + 64])) << 32) | (unsigned)(lane + 64);
  int* out = idx + (size_t)nd * KK;
  for (int r = 0; r < KK; ++r) {
    unsigned long long mk = key[0] < key[1] ? key[0] : key[1];
#pragma unroll
    for (int off = 32; off > 0; off >>= 1) {
      unsigned long long o = shfl_xor_u64(mk, off);
      if (o < mk) mk = o;
    }
    int wm = (int)(mk & 0xffffffffu);
    if (lane == 0) out[r] = wm;
    if ((wm & 63) == lane) key[wm >> 6] = ~0ull;
  }
}

// ---------------------------------------------------------------- node GEMM (scalar, layer-1 only)
__global__ __launch_bounds__(256) void node_gemm(const float* __restrict__ x,
                                                 const float* __restrict__ W,
                                                 float* __restrict__ p, float* __restrict__ q,
                                                 int Cin, int Cout) {
  int c = threadIdx.x;
  __shared__ float xr[128];
  for (int r = 0; r < 8; ++r) {
    int row = blockIdx.x * 8 + r;
    __syncthreads();
    for (int i = c; i < Cin; i += blockDim.x) xr[i] = x[(size_t)row * Cin + i];
    __syncthreads();
    float a = 0.f, qv = 0.f;
    for (int i = 0; i < Cin; ++i) {
      float xv = xr[i];
      a  = fmaf(xv, W[i * Cout + c], a);
      qv = fmaf(xv, W[(Cin + i) * Cout + c], qv);
    }
    p[(size_t)row * Cout + c] = a - qv;
    q[(size_t)row * Cout + c] = qv;
  }
}

// ---------------------------------------------------------------- W1 packing (32x32x16, node GEMM)
template<int K, int N>
__global__ __launch_bounds__(256) void pack_w1(const float* __restrict__ W1,
                                               u16* __restrict__ Wh, u16* __restrict__ Wl) {
  int t = blockIdx.x * 256 + threadIdx.x;
  if (t >= K * N) return;
  constexpr int C = N / 2;
  constexpr int NT2 = N / 32;
  int j = t & 7, lane = (t >> 3) & 63, tile = t >> 9;
  int nt = tile % NT2, kt = tile / NT2;
  int row = kt * 16 + (lane >> 5) * 8 + j;
  int col = nt * 32 + (lane & 31);
  float w;
  if (col < C) w = W1[row * C + col] - W1[(K + row) * C + col];
  else         w = W1[(K + row) * C + (col - C)];
  u16 h = bf16_rne_bits(w);
  float hf = __uint_as_float(((unsigned)h) << 16);
  Wh[t] = h;
  Wl[t] = bf16_rne_bits(w - hf);
}

// ---------------------------------------------------------------- MFMA node GEMM (layers 2,3)
template<int K, int N>
__global__ __launch_bounds__(256, 2) void node_gemm_mfma(
    const float* __restrict__ x, const u16* __restrict__ Wh, const u16* __restrict__ Wl,
    float* __restrict__ p, float* __restrict__ q) {
  constexpr int C = N / 2, KT = K / 16, NT2 = N / 32, NTQ = NT2 / 4;
  constexpr int CHK = NT2 * 64;
  __shared__ __align__(16) u16 Bst[2][2][CHK * 8];
  int tid = threadIdx.x, lane = tid & 63, wv = tid >> 6;
  int m = lane & 31, lh = lane >> 5;
  int rowBase = blockIdx.x * 32;
  const float* xr = x + (size_t)(rowBase + m) * K;

  floatx16 acc[NTQ];
#pragma unroll
  for (int nt = 0; nt < NTQ; ++nt)
#pragma unroll
    for (int r = 0; r < 16; ++r) acc[nt][r] = 0.f;

  float4 fxa[2], fxb[2];
  auto loadX = [&](int kt, int buf) {
    int c0 = kt * 16 + lh * 8;
    fxa[buf] = *(const float4*)(xr + c0);
    fxb[buf] = *(const float4*)(xr + c0 + 4);
  };
  auto stage = [&](int kt, int buf) {
    const ushort8_alias* srcH = (const ushort8_alias*)Wh + (size_t)kt * CHK;
    const ushort8_alias* srcL = (const ushort8_alias*)Wl + (size_t)kt * CHK;
    ushort8_alias* dH = (ushort8_alias*)Bst[buf][0];
    ushort8_alias* dL = (ushort8_alias*)Bst[buf][1];
    for (int i = tid; i < CHK; i += 256) { dH[i] = srcH[i]; dL[i] = srcL[i]; }
  };
  loadX(0, 0);
  stage(0, 0);
  __syncthreads();

#pragma unroll 2
  for (int kt = 0; kt < KT; ++kt) {
    int buf = kt & 1;
    if (kt + 1 < KT) { loadX(kt + 1, buf ^ 1); stage(kt + 1, buf ^ 1); }
    float hv[8];
    hv[0] = fxa[buf].x; hv[1] = fxa[buf].y; hv[2] = fxa[buf].z; hv[3] = fxa[buf].w;
    hv[4] = fxb[buf].x; hv[5] = fxb[buf].y; hv[6] = fxb[buf].z; hv[7] = fxb[buf].w;
    bf16x8 ah, al;
#pragma unroll
    for (int t = 0; t < 8; ++t) {
      __bf16 hb = (__bf16)hv[t];
      ah[t] = hb;
      al[t] = (__bf16)(hv[t] - (float)hb);
    }
#pragma unroll
    for (int nt = 0; nt < NTQ; ++nt) {
      int e = (wv * NTQ + nt) * 64 + lane;
      bf16x8 bh = __builtin_bit_cast(bf16x8, ((const ushort8_alias*)Bst[buf][0])[e]);
      bf16x8 bl = __builtin_bit_cast(bf16x8, ((const ushort8_alias*)Bst[buf][1])[e]);
      acc[nt] = __builtin_amdgcn_mfma_f32_32x32x16_bf16(ah, bh, acc[nt], 0, 0, 0);
      acc[nt] = __builtin_amdgcn_mfma_f32_32x32x16_bf16(al, bh, acc[nt], 0, 0, 0);
      acc[nt] = __builtin_amdgcn_mfma_f32_32x32x16_bf16(ah, bl, acc[nt], 0, 0, 0);
    }
    __syncthreads();
  }

#pragma unroll
  for (int nt = 0; nt < NTQ; ++nt) {
    int n = (wv * NTQ + nt) * 32 + m;
    float* dst = (n < C) ? p : q;
    int col = (n < C) ? n : n - C;
#pragma unroll
    for (int r = 0; r < 16; ++r) {
      int row = rowBase + (r & 3) + 8 * (r >> 2) + 4 * lh;
      dst[(size_t)row * C + col] = acc[nt][r];
    }
  }
}

// ---------------------------------------------------------------- BN1 stats (vectorized)
template<int C>
__global__ __launch_bounds__(256) void edge_stats1v(const float* __restrict__ p,
                                                    const float* __restrict__ q,
                                                    const float* __restrict__ b1,
                                                    const int* __restrict__ idx,
                                                    float* __restrict__ s1,
                                                    float* __restrict__ ss1) {
  constexpr int G = C / 4;
  constexpr int KL = 64 / G;
  int tid = threadIdx.x, lane = tid & 63, wv = tid >> 6;
  int nd = blockIdx.x * 4 + wv;
  int b = nd >> 7;
  int g = lane % G, kl = lane / G;

  __shared__ float sS[C], sSS[C];
  if (tid < C) { sS[tid] = 0.f; sSS[tid] = 0.f; }
  __syncthreads();

  const float* pr = p + (size_t)nd * C;
  float4 pv = *(const float4*)(pr + g * 4);
  float4 bv = *(const float4*)(b1 + g * 4);
  pv.x += bv.x; pv.y += bv.y; pv.z += bv.z; pv.w += bv.w;
  float4 s = {0, 0, 0, 0}, ss = {0, 0, 0, 0};
  const int* id = idx + (size_t)nd * KK;
#pragma unroll
  for (int k0 = 0; k0 < KK; k0 += KL) {
    int j = id[k0 + kl];
    float4 q4 = *(const float4*)(q + (size_t)(b * NN + j) * C + g * 4);
    float y;
    y = pv.x + q4.x; s.x += y; ss.x = fmaf(y, y, ss.x);
    y = pv.y + q4.y; s.y += y; ss.y = fmaf(y, y, ss.y);
    y = pv.z + q4.z; s.z += y; ss.z = fmaf(y, y, ss.z);
    y = pv.w + q4.w; s.w += y; ss.w = fmaf(y, y, ss.w);
  }
#pragma unroll
  for (int off = G; off < 64; off <<= 1) {
    s.x += __shfl_xor(s.x, off); ss.x += __shfl_xor(ss.x, off);
    s.y += __shfl_xor(s.y, off); ss.y += __shfl_xor(ss.y, off);
    s.z += __shfl_xor(s.z, off); ss.z += __shfl_xor(ss.z, off);
    s.w += __shfl_xor(s.w, off); ss.w += __shfl_xor(ss.w, off);
  }
  if (kl == 0) {
    atomicAdd(&sS[g * 4 + 0], s.x); atomicAdd(&sSS[g * 4 + 0], ss.x);
    atomicAdd(&sS[g * 4 + 1], s.y); atomicAdd(&sSS[g * 4 + 1], ss.y);
    atomicAdd(&sS[g * 4 + 2], s.z); atomicAdd(&sSS[g * 4 + 2], ss.z);
    atomicAdd(&sS[g * 4 + 3], s.w); atomicAdd(&sSS[g * 4 + 3], ss.w);
  }
  __syncthreads();
  if (tid < C) {
    atomicAdd(&s1[tid], sS[tid]);
    atomicAdd(&ss1[tid], sSS[tid]);
  }
}

// ---------------------------------------------------------------- W2 packing (16x16x32)
template<int C>
__global__ __launch_bounds__(256) void pack_w2(const float* __restrict__ W,
                                               u16* __restrict__ Wh, u16* __restrict__ Wl) {
  int t = blockIdx.x * 256 + threadIdx.x;
  if (t >= C * C) return;
  constexpr int NT = C / 16;
  int j = t & 7, lane = (t >> 3) & 63, tile = t >> 9;
  int nt = tile % NT, kt = tile / NT;
  int row = kt * 32 + (lane >> 4) * 8 + j;
  int col = nt * 16 + (lane & 15);
  float w = W[row * C + col];
  u16 h = bf16_rne_bits(w);
  float hf = __uint_as_float(((unsigned)h) << 16);
  Wh[t] = h;
  Wl[t] = bf16_rne_bits(w - hf);
}

// ---------------------------------------------------------------- MFMA edge GEMM2 v8
// v7 with windowed A-build: only the current window's CK=2 A k-tiles are live
// (16 VGPRs, constant indices) — total gather traffic unchanged (each channel
// chunk read once), but no 64-VGPR A array for the allocator to spill.
// BN1 scale/shift computed in-block from s1/ss1 (kills bn_params dispatch).
template<int C>
__global__ __launch_bounds__(256, (C > 128) ? 3 : 4) void edge_gemm2_v8(
    const float* __restrict__ p, const float* __restrict__ q,
    const int* __restrict__ idx,
    const float* __restrict__ s1, const float* __restrict__ ss1,
    const float* __restrict__ g1, const float* __restrict__ e1,
    const float* __restrict__ b1,
    const u16* __restrict__ Wh, const u16* __restrict__ Wl,
    const float* __restrict__ b2,
    float* __restrict__ zmax, float* __restrict__ zmin,
    float* __restrict__ s2, float* __restrict__ ss2) {
  constexpr int KT = C / 32;                 // k-tiles (K=32 each): 8,4,2
  constexpr int NT = C / 16;                 // global n-tiles
  constexpr int NSLICE = (C > 128) ? 2 : 1;
  constexpr int NCOL = C / NSLICE;           // 128,128,64
  constexpr int NTS = NCOL / 16;             // n-tiles per slice: 8,8,4
  constexpr int CK = 2;                      // k-tiles per LDS window
  constexpr int NWIN = KT / CK;              // 4,2,1
  constexpr int CCH = CK * NTS * 2 * 64;     // ushort8 chunks per window
  __shared__ __align__(16) u16 Bst[CCH * 8];
  __shared__ float sScl[C], sShf[C];

  int tid = threadIdx.x, lane = tid & 63, wv = tid >> 6;
  int r = lane & 15, kseg = lane >> 4;

  int bid = blockIdx.x;
  int g = bid / NSLICE, slice = bid % NSLICE;
  // XCD swizzle: groups of a batch share an XCD for q-slab L2 locality.
  int u = g >> 3, xcd = g & 7;
  int b = xcd + 8 * (u >> 5);
  int nodeBase = b * NN + (u & 31) * 4;
  int nd = nodeBase + wv;

  // BN1 params (bias1 folded into shift)
  if (tid < C) {
    float mean = s1[tid] / (float)MEDGE;
    float var = ss1[tid] / (float)MEDGE - mean * mean;
    if (var < 0.f) var = 0.f;
    float sc = g1[tid] * rsqrtf(var + 1e-5f);
    sScl[tid] = sc;
    sShf[tid] = e1[tid] - mean * sc + sc * b1[tid];
  }

  int j = idx[(size_t)nd * KK + r];
  const float* pr = p + (size_t)nd * C;
  const float* qr = q + (size_t)(b * NN + j) * C;

  floatx4 acc[NTS];
#pragma unroll
  for (int nt = 0; nt < NTS; ++nt) {
    float bv = b2[slice * NCOL + nt * 16 + r];
    acc[nt] = {bv, bv, bv, bv};
  }

  // ---- K-loop over LDS windows; A built per-window (constant indices)
#pragma unroll
  for (int w = 0; w < NWIN; ++w) {
    if (w > 0) __syncthreads();  // previous window's reads complete
    for (int i = tid; i < CCH; i += 256) {
      int c = i & 63, h = (i >> 6) & 1, rest = i >> 7;   // rest = kk*NTS+nt
      int nt = rest % NTS, kk = rest / NTS;
      const ushort8_alias* src = h ? (const ushort8_alias*)Wl : (const ushort8_alias*)Wh;
      ((ushort8_alias*)Bst)[i] = src[((w * CK + kk) * NT + slice * NTS + nt) * 64 + c];
    }
    __syncthreads();  // stage complete (w==0: also sScl/sShf complete)

    bf16x8 Ah[CK], Al[CK];
#pragma unroll
    for (int kk = 0; kk < CK; ++kk) {
      int c0 = (w * CK + kk) * 32 + kseg * 8;
      float4 pa = *(const float4*)(pr + c0);
      float4 pb = *(const float4*)(pr + c0 + 4);
      float4 qa = *(const float4*)(qr + c0);
      float4 qb = *(const float4*)(qr + c0 + 4);
      float4 sa = *(const float4*)(sScl + c0);
      float4 sb = *(const float4*)(sScl + c0 + 4);
      float4 ta = *(const float4*)(sShf + c0);
      float4 tb = *(const float4*)(sShf + c0 + 4);
      float hv[8];
      hv[0] = fmaxf(fmaf(pa.x + qa.x, sa.x, ta.x), 0.f);
      hv[1] = fmaxf(fmaf(pa.y + qa.y, sa.y, ta.y), 0.f);
      hv[2] = fmaxf(fmaf(pa.z + qa.z, sa.z, ta.z), 0.f);
      hv[3] = fmaxf(fmaf(pa.w + qa.w, sa.w, ta.w), 0.f);
      hv[4] = fmaxf(fmaf(pb.x + qb.x, sb.x, tb.x), 0.f);
      hv[5] = fmaxf(fmaf(pb.y + qb.y, sb.y, tb.y), 0.f);
      hv[6] = fmaxf(fmaf(pb.z + qb.z, sb.z, tb.z), 0.f);
      hv[7] = fmaxf(fmaf(pb.w + qb.w, sb.w, tb.w), 0.f);
#pragma unroll
      for (int t = 0; t < 8; ++t) {
        __bf16 hb = (__bf16)hv[t];
        Ah[kk][t] = hb;
        Al[kk][t] = (__bf16)(hv[t] - (float)hb);
      }
    }

#pragma unroll
    for (int kk = 0; kk < CK; ++kk) {
#pragma unroll
      for (int nt = 0; nt < NTS; ++nt) {
        int base = (kk * NTS + nt) * 128 + lane;
        bf16x8 bh = __builtin_bit_cast(bf16x8, ((const ushort8_alias*)Bst)[base]);
        bf16x8 bl = __builtin_bit_cast(bf16x8, ((const ushort8_alias*)Bst)[base + 64]);
        acc[nt] = __builtin_amdgcn_mfma_f32_16x16x32_bf16(Ah[kk], bh, acc[nt], 0, 0, 0);
        acc[nt] = __builtin_amdgcn_mfma_f32_16x16x32_bf16(Al[kk], bh, acc[nt], 0, 0, 0);
        acc[nt] = __builtin_amdgcn_mfma_f32_16x16x32_bf16(Ah[kk], bl, acc[nt], 0, 0, 0);
      }
    }
  }

  // ---- epilogue (reuse LDS for stats)
  __syncthreads();
  float* sS = (float*)Bst;
  float* sSS = sS + NCOL;
  if (tid < NCOL) { sS[tid] = 0.f; sSS[tid] = 0.f; }
  __syncthreads();

#pragma unroll
  for (int nt = 0; nt < NTS; ++nt) {
    float s = 0.f, ss = 0.f, mx = -INFINITY, mn = INFINITY;
#pragma unroll
    for (int gi = 0; gi < 4; ++gi) {
      float z = acc[nt][gi];
      s += z; ss = fmaf(z, z, ss);
      mx = fmaxf(mx, z); mn = fminf(mn, z);
    }
    mx = fmaxf(mx, __shfl_xor(mx, 16)); mn = fminf(mn, __shfl_xor(mn, 16));
    s += __shfl_xor(s, 16); ss += __shfl_xor(ss, 16);
    mx = fmaxf(mx, __shfl_xor(mx, 32)); mn = fminf(mn, __shfl_xor(mn, 32));
    s += __shfl_xor(s, 32); ss += __shfl_xor(ss, 32);
    if (kseg == 0) {
      int colL = nt * 16 + r;
      int col = slice * NCOL + colL;
      zmax[(size_t)nd * C + col] = mx;
      zmin[(size_t)nd * C + col] = mn;
      atomicAdd(&sS[colL], s);
      atomicAdd(&sSS[colL], ss);
    }
  }
  __syncthreads();
  if (tid < NCOL) {
    atomicAdd(&s2[slice * NCOL + tid], sS[tid]);
    atomicAdd(&ss2[slice * NCOL + tid], sSS[tid]);
  }
}

// ---------------------------------------------------------------- finalize (BN2 params folded in)
__global__ __launch_bounds__(256) void finalize2_kernel(const float* __restrict__ zmax,
                                                        const float* __restrict__ zmin,
                                                        const float* __restrict__ s2,
                                                        const float* __restrict__ ss2,
                                                        const float* __restrict__ g2,
                                                        const float* __restrict__ e2,
                                                        float* __restrict__ out, int Cmask) {
  int t = blockIdx.x * 256 + threadIdx.x;
  int c = t & Cmask;
  float mean = s2[c] / (float)MEDGE;
  float var = ss2[c] / (float)MEDGE - mean * mean;
  if (var < 0.f) var = 0.f;
  float scl = g2[c] * rsqrtf(var + 1e-5f);
  float shf = e2[c] - mean * scl;
  float v = (scl >= 0.f) ? zmax[t] : zmin[t];
  out[t] = fmaxf(fmaf(v, scl, shf), 0.f);
}

// ---------------------------------------------------------------- pooling
__global__ __launch_bounds__(256) void pool_kernel(const float* __restrict__ h,
                                                   float* __restrict__ pooled) {
  int b = blockIdx.x, c = threadIdx.x;
  float s = 0.f, mx = -INFINITY;
  for (int n = 0; n < NN; ++n) {
    float v = h[(size_t)(b * NN + n) * 256 + c];
    s += v;
    mx = fmaxf(mx, v);
  }
  pooled[b * 512 + c] = s * (1.f / 128.f);
  pooled[b * 512 + 256 + c] = mx;
}

// ---------------------------------------------------------------- FC tail
__global__ __launch_bounds__(256) void fc1_fused(const float* __restrict__ pooled,
                                                 const float* __restrict__ W,
                                                 const float* __restrict__ bias,
                                                 float* __restrict__ t1raw,
                                                 float* __restrict__ fs, float* __restrict__ fss) {
  int b = blockIdx.x, c = threadIdx.x;
  __shared__ float row[512];
  row[c] = pooled[b * 512 + c];
  row[c + 256] = pooled[b * 512 + 256 + c];
  __syncthreads();
  float acc = bias[c];
  for (int i = 0; i < 512; ++i) acc = fmaf(row[i], W[i * 256 + c], acc);
  t1raw[b * 256 + c] = acc;
  atomicAdd(&fs[c], acc);
  atomicAdd(&fss[c], acc * acc);
}

__global__ __launch_bounds__(256) void fc2_fused(const float* __restrict__ t1raw,
                                                 const float* __restrict__ fs,
                                                 const float* __restrict__ fss,
                                                 const float* __restrict__ g1,
                                                 const float* __restrict__ e1,
                                                 const float* __restrict__ W,
                                                 const float* __restrict__ bias,
                                                 float* __restrict__ t2raw,
                                                 float* __restrict__ gs, float* __restrict__ gss) {
  int b = blockIdx.x, c = threadIdx.x;
  __shared__ float row[256];
  {
    float mean = fs[c] / 128.f;
    float var = fss[c] / 128.f - mean * mean;
    if (var < 0.f) var = 0.f;
    float scl = g1[c] * rsqrtf(var + 1e-5f);
    float shf = e1[c] - mean * scl;
    row[c] = fmaxf(fmaf(t1raw[b * 256 + c], scl, shf), 0.f);
  }
  __syncthreads();
  if (c < 128) {
    float acc = bias[c];
    for (int i = 0; i < 256; ++i) acc = fmaf(row[i], W[i * 128 + c], acc);
    t2raw[b * 128 + c] = acc;
    atomicAdd(&gs[c], acc);
    atomicAdd(&gss[c], acc * acc);
  }
}

__global__ __launch_bounds__(256) void fc3_fused(const float* __restrict__ t2raw,
                                                 const float* __restrict__ gs,
                                                 const float* __restrict__ gss,
                                                 const float* __restrict__ g2,
                                                 const float* __restrict__ e2,
                                                 const float* __restrict__ W,
                                                 const float* __restrict__ bias,
                                                 float* __restrict__ out) {
  __shared__ float row[128 * 2];
  int t = threadIdx.x;
  if (t < 128) {
    float mean = gs[t] / 128.f;
    float var = gss[t] / 128.f - mean * mean;
    if (var < 0.f) var = 0.f;
    float scl = g2[t] * rsqrtf(var + 1e-5f);
    row[t] = scl;
    row[128 + t] = e2[t] - mean * scl;
  }
  __syncthreads();
  int b = t >> 1, jj = t & 1;
  float acc = bias[jj];
  for (int r = 0; r < 128; ++r) {
    float v = fmaxf(fmaf(t2raw[b * 128 + r], row[r], row[128 + r]), 0.f);
    acc = fmaf(v, W[r * 2 + jj], acc);
  }
  out[t] = acc;
}

// ---------------------------------------------------------------- per-layer driver

struct LayerPtrs {
  int* idx; float *p, *q, *zmx, *zmn, *stats, *D;
  u16 *Wh, *Wl, *Wh1, *Wl1;
};

template<int Cin, int C>
static void run_edgeconv(const float* xin,
                         const float* W1, const float* b1, const float* g1, const float* e1,
                         const float* W2, const float* b2, const float* g2, const float* e2,
                         float* hout, const LayerPtrs& L, hipStream_t stream) {
  float* s1 = L.stats;
  float* ss1 = L.stats + 256;
  float* s2 = L.stats + 512;
  float* ss2 = L.stats + 768;

  (void)hipMemsetAsync(L.stats, 0, 4 * 256 * sizeof(float), stream);
  dist_kernel<Cin><<<dim3(BB * 4), dim3(256), 0, stream>>>(xin, L.D);
  select_kernel<<<dim3(MNODE / 4), dim3(256), 0, stream>>>(L.D, L.idx);
  if constexpr (Cin >= 16) {
    pack_w1<Cin, 2 * C><<<dim3((Cin * 2 * C + 255) / 256), dim3(256), 0, stream>>>(W1, L.Wh1, L.Wl1);
    node_gemm_mfma<Cin, 2 * C><<<dim3(MNODE / 32), dim3(256), 0, stream>>>(xin, L.Wh1, L.Wl1, L.p, L.q);
  } else {
    node_gemm<<<dim3(MNODE / 8), dim3(C), 0, stream>>>(xin, W1, L.p, L.q, Cin, C);
  }
  pack_w2<C><<<dim3((C * C + 255) / 256), dim3(256), 0, stream>>>(W2, L.Wh, L.Wl);
  edge_stats1v<C><<<dim3(MNODE / 4), dim3(256), 0, stream>>>(L.p, L.q, b1, L.idx, s1, ss1);
  constexpr int NSLICE = (C > 128) ? 2 : 1;
  edge_gemm2_v8<C><<<dim3((MNODE / 4) * NSLICE), dim3(256), 0, stream>>>(
      L.p, L.q, L.idx, s1, ss1, g1, e1, b1, L.Wh, L.Wl, b2, L.zmx, L.zmn, s2, ss2);
  finalize2_kernel<<<dim3(MNODE * C / 256), dim3(256), 0, stream>>>(
      L.zmx, L.zmn, s2, ss2, g2, e2, hout, C - 1);
}

// ---------------------------------------------------------------- launch

extern "C" void kernel_launch(void* const* d_in, const int* in_sizes, int n_in,
                              void* d_out, int out_size, void* d_ws, size_t ws_size,
                              hipStream_t stream) {
  const float* x   = (const float*)d_in[0];
  const float* w11 = (const float*)d_in[1];
  const float* b11 = (const float*)d_in[2];
  const float* g11 = (const float*)d_in[3];
  const float* e11 = (const float*)d_in[4];
  const float* w12 = (const float*)d_in[5];
  const float* b12 = (const float*)d_in[6];
  const float* g12 = (const float*)d_in[7];
  const float* e12 = (const float*)d_in[8];
  const float* w21 = (const float*)d_in[9];
  const float* b21 = (const float*)d_in[10];
  const float* g21 = (const float*)d_in[11];
  const float* e21 = (const float*)d_in[12];
  const float* w22 = (const float*)d_in[13];
  const float* b22 = (const float*)d_in[14];
  const float* g22 = (const float*)d_in[15];
  const float* e22 = (const float*)d_in[16];
  const float* w31 = (const float*)d_in[17];
  const float* b31 = (const float*)d_in[18];
  const float* g31 = (const float*)d_in[19];
  const float* e31 = (const float*)d_in[20];
  const float* w32 = (const float*)d_in[21];
  const float* b32 = (const float*)d_in[22];
  const float* g32 = (const float*)d_in[23];
  const float* e32 = (const float*)d_in[24];
  const float* fw1 = (const float*)d_in[25];
  const float* fb1 = (const float*)d_in[26];
  const float* fg1 = (const float*)d_in[27];
  const float* fe1 = (const float*)d_in[28];
  const float* fw2 = (const float*)d_in[29];
  const float* fb2 = (const float*)d_in[30];
  const float* fg2 = (const float*)d_in[31];
  const float* fe2 = (const float*)d_in[32];
  const float* fw3 = (const float*)d_in[33];
  const float* fb3 = (const float*)d_in[34];

  char* wsb = (char*)d_ws;
  size_t o = 0;
  auto alloc = [&](size_t bytes) -> void* {
    void* r = wsb + o;
    o += (bytes + 255) & ~(size_t)255;
    return r;
  };
  LayerPtrs L;
  L.idx   = (int*)  alloc((size_t)MNODE * KK * sizeof(int));
  L.p     = (float*)alloc((size_t)MNODE * 256 * sizeof(float));
  L.q     = (float*)alloc((size_t)MNODE * 256 * sizeof(float));
  L.zmx   = (float*)alloc((size_t)MNODE * 256 * sizeof(float));
  L.zmn   = (float*)alloc((size_t)MNODE * 256 * sizeof(float));
  L.stats = (float*)alloc(8 * 256 * sizeof(float));
  L.D     = (float*)alloc((size_t)MNODE * NN * sizeof(float));
  L.Wh    = (u16*)  alloc((size_t)256 * 256 * sizeof(u16));
  L.Wl    = (u16*)  alloc((size_t)256 * 256 * sizeof(u16));
  L.Wh1   = (u16*)  alloc((size_t)128 * 512 * sizeof(u16));
  L.Wl1   = (u16*)  alloc((size_t)128 * 512 * sizeof(u16));
  float* h1buf   = (float*)alloc((size_t)MNODE * 64 * sizeof(float));
  float* h2buf   = (float*)alloc((size_t)MNODE * 128 * sizeof(float));
  float* h3buf   = (float*)alloc((size_t)MNODE * 256 * sizeof(float));
  float* pooled  = (float*)alloc(128 * 512 * sizeof(float));
  float* t1raw   = (float*)alloc(128 * 256 * sizeof(float));
  float* t2raw   = (float*)alloc(128 * 128 * sizeof(float));
  float* fcstats = (float*)alloc(8 * 256 * sizeof(float));

  float* fs  = fcstats;
  float* fss = fcstats + 256;
  float* gs  = fcstats + 512;
  float* gss = fcstats + 768;

  (void)hipMemsetAsync(fcstats, 0, 4 * 256 * sizeof(float), stream);

  run_edgeconv<6,   64 >(x,     w11, b11, g11, e11, w12, b12, g12, e12, h1buf, L, stream);
  run_edgeconv<64,  128>(h1buf, w21, b21, g21, e21, w22, b22, g22, e22, h2buf, L, stream);
  run_edgeconv<128, 256>(h2buf, w31, b31, g31, e31, w32, b32, g32, e32, h3buf, L, stream);

  pool_kernel<<<dim3(BB), dim3(256), 0, stream>>>(h3buf, pooled);
  fc1_fused<<<dim3(BB), dim3(256), 0, stream>>>(pooled, fw1, fb1, t1raw, fs, fss);
  fc2_fused<<<dim3(BB), dim3(256), 0, stream>>>(t1raw, fs, fss, fg1, fe1, fw2, fb2, t2raw, gs, gss);
  fc3_fused<<<dim3(1), dim3(256), 0, stream>>>(t2raw, gs, gss, fg2, fe2, fw3, fb3, (float*)d_out);
}

// Round 12
// 901.958 us; speedup vs baseline: 1.4881x; 1.2351x over previous
//
#include <hip/hip_runtime.h>
#include <math.h>

#define BB 128
#define NN 128
#define KK 16
#define MEDGE (BB*NN*KK)   // 262144 edges
#define MNODE (BB*NN)      // 16384 nodes

typedef __bf16 bf16x8 __attribute__((ext_vector_type(8)));
typedef float  floatx4 __attribute__((ext_vector_type(4)));
typedef float  floatx16 __attribute__((ext_vector_type(16)));
typedef unsigned short u16;
typedef u16 ushort8_alias __attribute__((ext_vector_type(8)));

// ---------------------------------------------------------------- utilities

__device__ __forceinline__ unsigned ord32(float f) {
  unsigned u = __float_as_uint(f);
  return (u & 0x80000000u) ? ~u : (u | 0x80000000u);
}

__device__ __forceinline__ unsigned long long shfl_xor_u64(unsigned long long v, int m) {
  unsigned lo = (unsigned)(v & 0xffffffffull);
  unsigned hi = (unsigned)(v >> 32);
  lo = __shfl_xor(lo, m, 64);
  hi = __shfl_xor(hi, m, 64);
  return (((unsigned long long)hi) << 32) | (unsigned long long)lo;
}

__device__ __forceinline__ u16 bf16_rne_bits(float x) {
  unsigned u = __float_as_uint(x);
  return (u16)((u + 0x7FFF + ((u >> 16) & 1)) >> 16);
}

// ---------------------------------------------------------------- fused kNN (dist + select)
// 2 blocks per batch (64 query rows each). x staged fully in LDS, Gram/dist
// computed with the SAME sequential-c fma order as before (bit-identical),
// D kept in LDS (never hits global), then per-wave top-16 selection.
template<int C>
__global__ __launch_bounds__(256) void knn_fused(const float* __restrict__ x,
                                                 int* __restrict__ idx) {
  constexpr int S = C + 2;
  constexpr int DS = NN + 2;
  __shared__ float xs[NN * S];
  __shared__ float sq[NN];
  __shared__ float Dl[64 * DS];
  int b = blockIdx.x >> 1, half = blockIdx.x & 1;
  const float* xb = x + (size_t)b * NN * C;
  int tid = threadIdx.x;

  // stage x (coalesced)
  for (int t = tid; t < NN * C; t += 256) {
    int row = t / C, c = t - row * C;
    xs[row * S + c] = xb[t];
  }
  __syncthreads();
  if (tid < NN) {
    const float* xr = xs + tid * S;
    float s = 0.f;
    for (int c = 0; c < C; ++c) s = fmaf(xr[c], xr[c], s);
    sq[tid] = s;
  }
  __syncthreads();

  // dist: 64 rows x 128 cols; thread = 8 rows x 4 cols
  int rg = tid >> 5, cg = tid & 31;
  int r0 = half * 64 + rg * 8;
  float acc[8][4];
#pragma unroll
  for (int i = 0; i < 8; ++i)
#pragma unroll
    for (int j = 0; j < 4; ++j) acc[i][j] = 0.f;
  for (int c = 0; c < C; c += 2) {
    float2 av[8], bv[4];
#pragma unroll
    for (int i = 0; i < 8; ++i) av[i] = *(const float2*)&xs[(r0 + i) * S + c];
#pragma unroll
    for (int j = 0; j < 4; ++j) bv[j] = *(const float2*)&xs[(cg + 32 * j) * S + c];
#pragma unroll
    for (int i = 0; i < 8; ++i)
#pragma unroll
      for (int j = 0; j < 4; ++j) {
        acc[i][j] = fmaf(av[i].x, bv[j].x, acc[i][j]);
        acc[i][j] = fmaf(av[i].y, bv[j].y, acc[i][j]);
      }
  }
#pragma unroll
  for (int i = 0; i < 8; ++i) {
    float sn = sq[r0 + i];
#pragma unroll
    for (int j = 0; j < 4; ++j) {
      int m = cg + 32 * j;
      Dl[(rg * 8 + i) * DS + m] = sn - 2.f * acc[i][j] + sq[m];
    }
  }
  __syncthreads();

  // selection: wave wv handles local rows wv*16 .. wv*16+15
  int lane = tid & 63, wv = tid >> 6;
  for (int t = 0; t < 16; ++t) {
    int lr = wv * 16 + t;
    int nd = b * NN + half * 64 + lr;
    unsigned long long key[2];
    key[0] = (((unsigned long long)ord32(Dl[lr * DS + lane])) << 32) | (unsigned)lane;
    key[1] = (((unsigned long long)ord32(Dl[lr * DS + lane + 64])) << 32) | (unsigned)(lane + 64);
    int* out = idx + (size_t)nd * KK;
    for (int r = 0; r < KK; ++r) {
      unsigned long long mk = key[0] < key[1] ? key[0] : key[1];
#pragma unroll
      for (int off = 32; off > 0; off >>= 1) {
        unsigned long long o = shfl_xor_u64(mk, off);
        if (o < mk) mk = o;
      }
      int wm = (int)(mk & 0xffffffffu);
      if (lane == 0) out[r] = wm;
      if ((wm & 63) == lane) key[wm >> 6] = ~0ull;
    }
  }
}

// ---------------------------------------------------------------- node GEMM (scalar, layer-1 only)
__global__ __launch_bounds__(256) void node_gemm(const float* __restrict__ x,
                                                 const float* __restrict__ W,
                                                 float* __restrict__ p, float* __restrict__ q,
                                                 int Cin, int Cout) {
  int c = threadIdx.x;
  __shared__ float xr[128];
  for (int r = 0; r < 8; ++r) {
    int row = blockIdx.x * 8 + r;
    __syncthreads();
    for (int i = c; i < Cin; i += blockDim.x) xr[i] = x[(size_t)row * Cin + i];
    __syncthreads();
    float a = 0.f, qv = 0.f;
    for (int i = 0; i < Cin; ++i) {
      float xv = xr[i];
      a  = fmaf(xv, W[i * Cout + c], a);
      qv = fmaf(xv, W[(Cin + i) * Cout + c], qv);
    }
    p[(size_t)row * Cout + c] = a - qv;
    q[(size_t)row * Cout + c] = qv;
  }
}

// ---------------------------------------------------------------- W1 packing (32x32x16, node GEMM)
template<int K, int N>
__global__ __launch_bounds__(256) void pack_w1(const float* __restrict__ W1,
                                               u16* __restrict__ Wh, u16* __restrict__ Wl) {
  int t = blockIdx.x * 256 + threadIdx.x;
  if (t >= K * N) return;
  constexpr int C = N / 2;
  constexpr int NT2 = N / 32;
  int j = t & 7, lane = (t >> 3) & 63, tile = t >> 9;
  int nt = tile % NT2, kt = tile / NT2;
  int row = kt * 16 + (lane >> 5) * 8 + j;
  int col = nt * 32 + (lane & 31);
  float w;
  if (col < C) w = W1[row * C + col] - W1[(K + row) * C + col];
  else         w = W1[(K + row) * C + (col - C)];
  u16 h = bf16_rne_bits(w);
  float hf = __uint_as_float(((unsigned)h) << 16);
  Wh[t] = h;
  Wl[t] = bf16_rne_bits(w - hf);
}

// ---------------------------------------------------------------- MFMA node GEMM (layers 2,3)
template<int K, int N>
__global__ __launch_bounds__(256, 2) void node_gemm_mfma(
    const float* __restrict__ x, const u16* __restrict__ Wh, const u16* __restrict__ Wl,
    float* __restrict__ p, float* __restrict__ q) {
  constexpr int C = N / 2, KT = K / 16, NT2 = N / 32, NTQ = NT2 / 4;
  constexpr int CHK = NT2 * 64;
  __shared__ __align__(16) u16 Bst[2][2][CHK * 8];
  int tid = threadIdx.x, lane = tid & 63, wv = tid >> 6;
  int m = lane & 31, lh = lane >> 5;
  int rowBase = blockIdx.x * 32;
  const float* xr = x + (size_t)(rowBase + m) * K;

  floatx16 acc[NTQ];
#pragma unroll
  for (int nt = 0; nt < NTQ; ++nt)
#pragma unroll
    for (int r = 0; r < 16; ++r) acc[nt][r] = 0.f;

  float4 fxa[2], fxb[2];
  auto loadX = [&](int kt, int buf) {
    int c0 = kt * 16 + lh * 8;
    fxa[buf] = *(const float4*)(xr + c0);
    fxb[buf] = *(const float4*)(xr + c0 + 4);
  };
  auto stage = [&](int kt, int buf) {
    const ushort8_alias* srcH = (const ushort8_alias*)Wh + (size_t)kt * CHK;
    const ushort8_alias* srcL = (const ushort8_alias*)Wl + (size_t)kt * CHK;
    ushort8_alias* dH = (ushort8_alias*)Bst[buf][0];
    ushort8_alias* dL = (ushort8_alias*)Bst[buf][1];
    for (int i = tid; i < CHK; i += 256) { dH[i] = srcH[i]; dL[i] = srcL[i]; }
  };
  loadX(0, 0);
  stage(0, 0);
  __syncthreads();

#pragma unroll 2
  for (int kt = 0; kt < KT; ++kt) {
    int buf = kt & 1;
    if (kt + 1 < KT) { loadX(kt + 1, buf ^ 1); stage(kt + 1, buf ^ 1); }
    float hv[8];
    hv[0] = fxa[buf].x; hv[1] = fxa[buf].y; hv[2] = fxa[buf].z; hv[3] = fxa[buf].w;
    hv[4] = fxb[buf].x; hv[5] = fxb[buf].y; hv[6] = fxb[buf].z; hv[7] = fxb[buf].w;
    bf16x8 ah, al;
#pragma unroll
    for (int t = 0; t < 8; ++t) {
      __bf16 hb = (__bf16)hv[t];
      ah[t] = hb;
      al[t] = (__bf16)(hv[t] - (float)hb);
    }
#pragma unroll
    for (int nt = 0; nt < NTQ; ++nt) {
      int e = (wv * NTQ + nt) * 64 + lane;
      bf16x8 bh = __builtin_bit_cast(bf16x8, ((const ushort8_alias*)Bst[buf][0])[e]);
      bf16x8 bl = __builtin_bit_cast(bf16x8, ((const ushort8_alias*)Bst[buf][1])[e]);
      acc[nt] = __builtin_amdgcn_mfma_f32_32x32x16_bf16(ah, bh, acc[nt], 0, 0, 0);
      acc[nt] = __builtin_amdgcn_mfma_f32_32x32x16_bf16(al, bh, acc[nt], 0, 0, 0);
      acc[nt] = __builtin_amdgcn_mfma_f32_32x32x16_bf16(ah, bl, acc[nt], 0, 0, 0);
    }
    __syncthreads();
  }

#pragma unroll
  for (int nt = 0; nt < NTQ; ++nt) {
    int n = (wv * NTQ + nt) * 32 + m;
    float* dst = (n < C) ? p : q;
    int col = (n < C) ? n : n - C;
#pragma unroll
    for (int r = 0; r < 16; ++r) {
      int row = rowBase + (r & 3) + 8 * (r >> 2) + 4 * lh;
      dst[(size_t)row * C + col] = acc[nt][r];
    }
  }
}

// ---------------------------------------------------------------- BN1 stats (banked atomics)
// stats layout (floats): s1b[8][256] | ss1b[8][256] | s2b[8][256] | ss2b[8][256]
template<int C>
__global__ __launch_bounds__(256) void edge_stats1v(const float* __restrict__ p,
                                                    const float* __restrict__ q,
                                                    const float* __restrict__ b1,
                                                    const int* __restrict__ idx,
                                                    float* __restrict__ statsL) {
  constexpr int G = C / 4;
  constexpr int KL = 64 / G;
  int tid = threadIdx.x, lane = tid & 63, wv = tid >> 6;
  int nd = blockIdx.x * 4 + wv;
  int b = nd >> 7;
  int g = lane % G, kl = lane / G;
  int bank = blockIdx.x & 7;

  __shared__ float sS[C], sSS[C];
  if (tid < C) { sS[tid] = 0.f; sSS[tid] = 0.f; }
  __syncthreads();

  const float* pr = p + (size_t)nd * C;
  float4 pv = *(const float4*)(pr + g * 4);
  float4 bv = *(const float4*)(b1 + g * 4);
  pv.x += bv.x; pv.y += bv.y; pv.z += bv.z; pv.w += bv.w;
  float4 s = {0, 0, 0, 0}, ss = {0, 0, 0, 0};
  const int* id = idx + (size_t)nd * KK;
#pragma unroll
  for (int k0 = 0; k0 < KK; k0 += KL) {
    int j = id[k0 + kl];
    float4 q4 = *(const float4*)(q + (size_t)(b * NN + j) * C + g * 4);
    float y;
    y = pv.x + q4.x; s.x += y; ss.x = fmaf(y, y, ss.x);
    y = pv.y + q4.y; s.y += y; ss.y = fmaf(y, y, ss.y);
    y = pv.z + q4.z; s.z += y; ss.z = fmaf(y, y, ss.z);
    y = pv.w + q4.w; s.w += y; ss.w = fmaf(y, y, ss.w);
  }
#pragma unroll
  for (int off = G; off < 64; off <<= 1) {
    s.x += __shfl_xor(s.x, off); ss.x += __shfl_xor(ss.x, off);
    s.y += __shfl_xor(s.y, off); ss.y += __shfl_xor(ss.y, off);
    s.z += __shfl_xor(s.z, off); ss.z += __shfl_xor(ss.z, off);
    s.w += __shfl_xor(s.w, off); ss.w += __shfl_xor(ss.w, off);
  }
  if (kl == 0) {
    atomicAdd(&sS[g * 4 + 0], s.x); atomicAdd(&sSS[g * 4 + 0], ss.x);
    atomicAdd(&sS[g * 4 + 1], s.y); atomicAdd(&sSS[g * 4 + 1], ss.y);
    atomicAdd(&sS[g * 4 + 2], s.z); atomicAdd(&sSS[g * 4 + 2], ss.z);
    atomicAdd(&sS[g * 4 + 3], s.w); atomicAdd(&sSS[g * 4 + 3], ss.w);
  }
  __syncthreads();
  if (tid < C) {
    atomicAdd(&statsL[bank * 256 + tid], sS[tid]);
    atomicAdd(&statsL[2048 + bank * 256 + tid], sSS[tid]);
  }
}

// ---------------------------------------------------------------- W2 packing (16x16x32)
template<int C>
__global__ __launch_bounds__(256) void pack_w2(const float* __restrict__ W,
                                               u16* __restrict__ Wh, u16* __restrict__ Wl) {
  int t = blockIdx.x * 256 + threadIdx.x;
  if (t >= C * C) return;
  constexpr int NT = C / 16;
  int j = t & 7, lane = (t >> 3) & 63, tile = t >> 9;
  int nt = tile % NT, kt = tile / NT;
  int row = kt * 32 + (lane >> 4) * 8 + j;
  int col = nt * 16 + (lane & 15);
  float w = W[row * C + col];
  u16 h = bf16_rne_bits(w);
  float hf = __uint_as_float(((unsigned)h) << 16);
  Wh[t] = h;
  Wl[t] = bf16_rne_bits(w - hf);
}

// ---------------------------------------------------------------- MFMA edge GEMM2 v9
// B-slice (64 cols, hi+lo, ALL of K) fully LDS-resident: ONE barrier, then a
// barrier-free K-loop: 4 affine gather loads -> A-build (transient regs, no
// indexed arrays) -> ds_read B -> 12 MFMAs per k-tile. acc = 16 VGPRs.
// Block = 8 waves = 8 nodes x one 64-col slice. Banked BN stats.
template<int C>
__global__ __launch_bounds__(512, 4) void edge_gemm2_v9(
    const float* __restrict__ p, const float* __restrict__ q,
    const int* __restrict__ idx,
    const float* __restrict__ statsL,   // banked s1/ss1 (+ s2/ss2 out)
    const float* __restrict__ g1, const float* __restrict__ e1,
    const float* __restrict__ b1,
    const u16* __restrict__ Wh, const u16* __restrict__ Wl,
    const float* __restrict__ b2,
    float* __restrict__ zmax, float* __restrict__ zmin,
    float* __restrict__ s2b, float* __restrict__ ss2b) {
  constexpr int KT = C / 32;                 // 8,4,2
  constexpr int NT = C / 16;
  constexpr int NSLICE = C / 64;             // 4,2,1
  constexpr int NCOL = 64, NTS = 4;
  constexpr int CCH = KT * NTS * 2 * 64;     // ushort8 chunks (4096/2048/1024)
  __shared__ __align__(16) u16 Bst[CCH * 8];
  __shared__ float sScl[C], sShf[C];
  __shared__ float sS[NCOL], sSS[NCOL];

  int tid = threadIdx.x, lane = tid & 63, wv = tid >> 6;
  int r = lane & 15, kseg = lane >> 4;

  int bid = blockIdx.x;
  int g = bid / NSLICE, slice = bid % NSLICE;
  int u = g >> 3, xcd = g & 7;
  int b = xcd + 8 * (u >> 4);
  int nodeBase = b * NN + (u & 15) * 8;
  int nd = nodeBase + wv;

  // BN1 params from banked stats (bias1 folded into shift)
  if (tid < C) {
    float s = 0.f, ssum = 0.f;
#pragma unroll
    for (int k = 0; k < 8; ++k) {
      s += statsL[k * 256 + tid];
      ssum += statsL[2048 + k * 256 + tid];
    }
    float mean = s / (float)MEDGE;
    float var = ssum / (float)MEDGE - mean * mean;
    if (var < 0.f) var = 0.f;
    float sc = g1[tid] * rsqrtf(var + 1e-5f);
    sScl[tid] = sc;
    sShf[tid] = e1[tid] - mean * sc + sc * b1[tid];
  }
  if (tid < NCOL) { sS[tid] = 0.f; sSS[tid] = 0.f; }

  int j = idx[(size_t)nd * KK + r];
  const float* pr = p + (size_t)nd * C;
  const float* qr = q + (size_t)(b * NN + j) * C;

  // stage full B slice (hi+lo, all K)
  for (int i = tid; i < CCH; i += 512) {
    int c = i & 63, h = (i >> 6) & 1, rest = i >> 7;   // rest = kt*NTS+nt
    int nt = rest % NTS, kt = rest / NTS;
    const ushort8_alias* src = h ? (const ushort8_alias*)Wl : (const ushort8_alias*)Wh;
    ((ushort8_alias*)Bst)[i] = src[((size_t)kt * NT + slice * NTS + nt) * 64 + c];
  }
  __syncthreads();  // the ONLY barrier before the K-loop

  floatx4 acc[NTS];
#pragma unroll
  for (int nt = 0; nt < NTS; ++nt) {
    float bv = b2[slice * NCOL + nt * 16 + r];
    acc[nt] = {bv, bv, bv, bv};
  }

#pragma unroll 2
  for (int kt = 0; kt < KT; ++kt) {
    int c0 = kt * 32 + kseg * 8;
    float4 pa = *(const float4*)(pr + c0);
    float4 pb = *(const float4*)(pr + c0 + 4);
    float4 qa = *(const float4*)(qr + c0);
    float4 qb = *(const float4*)(qr + c0 + 4);
    float4 sa = *(const float4*)(sScl + c0);
    float4 sb = *(const float4*)(sScl + c0 + 4);
    float4 ta = *(const float4*)(sShf + c0);
    float4 tb = *(const float4*)(sShf + c0 + 4);
    float hv[8];
    hv[0] = fmaxf(fmaf(pa.x + qa.x, sa.x, ta.x), 0.f);
    hv[1] = fmaxf(fmaf(pa.y + qa.y, sa.y, ta.y), 0.f);
    hv[2] = fmaxf(fmaf(pa.z + qa.z, sa.z, ta.z), 0.f);
    hv[3] = fmaxf(fmaf(pa.w + qa.w, sa.w, ta.w), 0.f);
    hv[4] = fmaxf(fmaf(pb.x + qb.x, sb.x, tb.x), 0.f);
    hv[5] = fmaxf(fmaf(pb.y + qb.y, sb.y, tb.y), 0.f);
    hv[6] = fmaxf(fmaf(pb.z + qb.z, sb.z, tb.z), 0.f);
    hv[7] = fmaxf(fmaf(pb.w + qb.w, sb.w, tb.w), 0.f);
    bf16x8 ah, al;
#pragma unroll
    for (int t = 0; t < 8; ++t) {
      __bf16 hb = (__bf16)hv[t];
      ah[t] = hb;
      al[t] = (__bf16)(hv[t] - (float)hb);
    }
#pragma unroll
    for (int nt = 0; nt < NTS; ++nt) {
      int base = (kt * NTS + nt) * 128 + lane;
      bf16x8 bh = __builtin_bit_cast(bf16x8, ((const ushort8_alias*)Bst)[base]);
      bf16x8 bl = __builtin_bit_cast(bf16x8, ((const ushort8_alias*)Bst)[base + 64]);
      acc[nt] = __builtin_amdgcn_mfma_f32_16x16x32_bf16(ah, bh, acc[nt], 0, 0, 0);
      acc[nt] = __builtin_amdgcn_mfma_f32_16x16x32_bf16(al, bh, acc[nt], 0, 0, 0);
      acc[nt] = __builtin_amdgcn_mfma_f32_16x16x32_bf16(ah, bl, acc[nt], 0, 0, 0);
    }
  }

  // epilogue: C/D col = lane&15, row (neighbor) = kseg*4+reg
  int bank = blockIdx.x & 7;
#pragma unroll
  for (int nt = 0; nt < NTS; ++nt) {
    float s = 0.f, ss = 0.f, mx = -INFINITY, mn = INFINITY;
#pragma unroll
    for (int gi = 0; gi < 4; ++gi) {
      float z = acc[nt][gi];
      s += z; ss = fmaf(z, z, ss);
      mx = fmaxf(mx, z); mn = fminf(mn, z);
    }
    mx = fmaxf(mx, __shfl_xor(mx, 16)); mn = fminf(mn, __shfl_xor(mn, 16));
    s += __shfl_xor(s, 16); ss += __shfl_xor(ss, 16);
    mx = fmaxf(mx, __shfl_xor(mx, 32)); mn = fminf(mn, __shfl_xor(mn, 32));
    s += __shfl_xor(s, 32); ss += __shfl_xor(ss, 32);
    if (kseg == 0) {
      int colL = nt * 16 + r;
      int col = slice * NCOL + colL;
      zmax[(size_t)nd * C + col] = mx;
      zmin[(size_t)nd * C + col] = mn;
      atomicAdd(&sS[colL], s);
      atomicAdd(&sSS[colL], ss);
    }
  }
  __syncthreads();
  if (tid < NCOL) {
    atomicAdd(&s2b[bank * 256 + slice * NCOL + tid], sS[tid]);
    atomicAdd(&ss2b[bank * 256 + slice * NCOL + tid], sSS[tid]);
  }
}

// ---------------------------------------------------------------- finalize (banked BN2 params)
__global__ __launch_bounds__(256) void finalize2_kernel(const float* __restrict__ zmax,
                                                        const float* __restrict__ zmin,
                                                        const float* __restrict__ s2b,
                                                        const float* __restrict__ ss2b,
                                                        const float* __restrict__ g2,
                                                        const float* __restrict__ e2,
                                                        float* __restrict__ out, int Cmask) {
  int t = blockIdx.x * 256 + threadIdx.x;
  int c = t & Cmask;
  float s = 0.f, ss = 0.f;
#pragma unroll
  for (int k = 0; k < 8; ++k) {
    s += s2b[k * 256 + c];
    ss += ss2b[k * 256 + c];
  }
  float mean = s / (float)MEDGE;
  float var = ss / (float)MEDGE - mean * mean;
  if (var < 0.f) var = 0.f;
  float scl = g2[c] * rsqrtf(var + 1e-5f);
  float shf = e2[c] - mean * scl;
  float v = (scl >= 0.f) ? zmax[t] : zmin[t];
  out[t] = fmaxf(fmaf(v, scl, shf), 0.f);
}

// ---------------------------------------------------------------- pooling
__global__ __launch_bounds__(256) void pool_kernel(const float* __restrict__ h,
                                                   float* __restrict__ pooled) {
  int b = blockIdx.x, c = threadIdx.x;
  float s = 0.f, mx = -INFINITY;
  for (int n = 0; n < NN; ++n) {
    float v = h[(size_t)(b * NN + n) * 256 + c];
    s += v;
    mx = fmaxf(mx, v);
  }
  pooled[b * 512 + c] = s * (1.f / 128.f);
  pooled[b * 512 + 256 + c] = mx;
}

// ---------------------------------------------------------------- FC tail
__global__ __launch_bounds__(256) void fc1_fused(const float* __restrict__ pooled,
                                                 const float* __restrict__ W,
                                                 const float* __restrict__ bias,
                                                 float* __restrict__ t1raw,
                                                 float* __restrict__ fs, float* __restrict__ fss) {
  int b = blockIdx.x, c = threadIdx.x;
  __shared__ float row[512];
  row[c] = pooled[b * 512 + c];
  row[c + 256] = pooled[b * 512 + 256 + c];
  __syncthreads();
  float acc = bias[c];
  for (int i = 0; i < 512; ++i) acc = fmaf(row[i], W[i * 256 + c], acc);
  t1raw[b * 256 + c] = acc;
  atomicAdd(&fs[c], acc);
  atomicAdd(&fss[c], acc * acc);
}

__global__ __launch_bounds__(256) void fc2_fused(const float* __restrict__ t1raw,
                                                 const float* __restrict__ fs,
                                                 const float* __restrict__ fss,
                                                 const float* __restrict__ g1,
                                                 const float* __restrict__ e1,
                                                 const float* __restrict__ W,
                                                 const float* __restrict__ bias,
                                                 float* __restrict__ t2raw,
                                                 float* __restrict__ gs, float* __restrict__ gss) {
  int b = blockIdx.x, c = threadIdx.x;
  __shared__ float row[256];
  {
    float mean = fs[c] / 128.f;
    float var = fss[c] / 128.f - mean * mean;
    if (var < 0.f) var = 0.f;
    float scl = g1[c] * rsqrtf(var + 1e-5f);
    float shf = e1[c] - mean * scl;
    row[c] = fmaxf(fmaf(t1raw[b * 256 + c], scl, shf), 0.f);
  }
  __syncthreads();
  if (c < 128) {
    float acc = bias[c];
    for (int i = 0; i < 256; ++i) acc = fmaf(row[i], W[i * 128 + c], acc);
    t2raw[b * 128 + c] = acc;
    atomicAdd(&gs[c], acc);
    atomicAdd(&gss[c], acc * acc);
  }
}

__global__ __launch_bounds__(256) void fc3_fused(const float* __restrict__ t2raw,
                                                 const float* __restrict__ gs,
                                                 const float* __restrict__ gss,
                                                 const float* __restrict__ g2,
                                                 const float* __restrict__ e2,
                                                 const float* __restrict__ W,
                                                 const float* __restrict__ bias,
                                                 float* __restrict__ out) {
  __shared__ float row[128 * 2];
  int t = threadIdx.x;
  if (t < 128) {
    float mean = gs[t] / 128.f;
    float var = gss[t] / 128.f - mean * mean;
    if (var < 0.f) var = 0.f;
    float scl = g2[t] * rsqrtf(var + 1e-5f);
    row[t] = scl;
    row[128 + t] = e2[t] - mean * scl;
  }
  __syncthreads();
  int b = t >> 1, jj = t & 1;
  float acc = bias[jj];
  for (int r = 0; r < 128; ++r) {
    float v = fmaxf(fmaf(t2raw[b * 128 + r], row[r], row[128 + r]), 0.f);
    acc = fmaf(v, W[r * 2 + jj], acc);
  }
  out[t] = acc;
}

// ---------------------------------------------------------------- per-layer driver

struct LayerPtrs {
  int* idx; float *p, *q, *zmx, *zmn;
  u16 *Wh, *Wl, *Wh1, *Wl1;
};

template<int Cin, int C>
static void run_edgeconv(const float* xin,
                         const float* W1, const float* b1, const float* g1, const float* e1,
                         const float* W2, const float* b2, const float* g2, const float* e2,
                         float* hout, float* statsL, const LayerPtrs& L, hipStream_t stream) {
  float* s2b = statsL + 4096;
  float* ss2b = statsL + 6144;

  knn_fused<Cin><<<dim3(BB * 2), dim3(256), 0, stream>>>(xin, L.idx);
  if constexpr (Cin >= 16) {
    pack_w1<Cin, 2 * C><<<dim3((Cin * 2 * C + 255) / 256), dim3(256), 0, stream>>>(W1, L.Wh1, L.Wl1);
    node_gemm_mfma<Cin, 2 * C><<<dim3(MNODE / 32), dim3(256), 0, stream>>>(xin, L.Wh1, L.Wl1, L.p, L.q);
  } else {
    node_gemm<<<dim3(MNODE / 8), dim3(C), 0, stream>>>(xin, W1, L.p, L.q, Cin, C);
  }
  pack_w2<C><<<dim3((C * C + 255) / 256), dim3(256), 0, stream>>>(W2, L.Wh, L.Wl);
  edge_stats1v<C><<<dim3(MNODE / 4), dim3(256), 0, stream>>>(L.p, L.q, b1, L.idx, statsL);
  constexpr int NSLICE = C / 64;
  edge_gemm2_v9<C><<<dim3((MNODE / 8) * NSLICE), dim3(512), 0, stream>>>(
      L.p, L.q, L.idx, statsL, g1, e1, b1, L.Wh, L.Wl, b2, L.zmx, L.zmn, s2b, ss2b);
  finalize2_kernel<<<dim3(MNODE * C / 256), dim3(256), 0, stream>>>(
      L.zmx, L.zmn, s2b, ss2b, g2, e2, hout, C - 1);
}

// ---------------------------------------------------------------- launch

extern "C" void kernel_launch(void* const* d_in, const int* in_sizes, int n_in,
                              void* d_out, int out_size, void* d_ws, size_t ws_size,
                              hipStream_t stream) {
  const float* x   = (const float*)d_in[0];
  const float* w11 = (const float*)d_in[1];
  const float* b11 = (const float*)d_in[2];
  const float* g11 = (const float*)d_in[3];
  const float* e11 = (const float*)d_in[4];
  const float* w12 = (const float*)d_in[5];
  const float* b12 = (const float*)d_in[6];
  const float* g12 = (const float*)d_in[7];
  const float* e12 = (const float*)d_in[8];
  const float* w21 = (const float*)d_in[9];
  const float* b21 = (const float*)d_in[10];
  const float* g21 = (const float*)d_in[11];
  const float* e21 = (const float*)d_in[12];
  const float* w22 = (const float*)d_in[13];
  const float* b22 = (const float*)d_in[14];
  const float* g22 = (const float*)d_in[15];
  const float* e22 = (const float*)d_in[16];
  const float* w31 = (const float*)d_in[17];
  const float* b31 = (const float*)d_in[18];
  const float* g31 = (const float*)d_in[19];
  const float* e31 = (const float*)d_in[20];
  const float* w32 = (const float*)d_in[21];
  const float* b32 = (const float*)d_in[22];
  const float* g32 = (const float*)d_in[23];
  const float* e32 = (const float*)d_in[24];
  const float* fw1 = (const float*)d_in[25];
  const float* fb1 = (const float*)d_in[26];
  const float* fg1 = (const float*)d_in[27];
  const float* fe1 = (const float*)d_in[28];
  const float* fw2 = (const float*)d_in[29];
  const float* fb2 = (const float*)d_in[30];
  const float* fg2 = (const float*)d_in[31];
  const float* fe2 = (const float*)d_in[32];
  const float* fw3 = (const float*)d_in[33];
  const float* fb3 = (const float*)d_in[34];

  char* wsb = (char*)d_ws;
  size_t o = 0;
  auto alloc = [&](size_t bytes) -> void* {
    void* r = wsb + o;
    o += (bytes + 255) & ~(size_t)255;
    return r;
  };
  LayerPtrs L;
  L.idx   = (int*)  alloc((size_t)MNODE * KK * sizeof(int));
  L.p     = (float*)alloc((size_t)MNODE * 256 * sizeof(float));
  L.q     = (float*)alloc((size_t)MNODE * 256 * sizeof(float));
  L.zmx   = (float*)alloc((size_t)MNODE * 256 * sizeof(float));
  L.zmn   = (float*)alloc((size_t)MNODE * 256 * sizeof(float));
  L.Wh    = (u16*)  alloc((size_t)256 * 256 * sizeof(u16));
  L.Wl    = (u16*)  alloc((size_t)256 * 256 * sizeof(u16));
  L.Wh1   = (u16*)  alloc((size_t)128 * 512 * sizeof(u16));
  L.Wl1   = (u16*)  alloc((size_t)128 * 512 * sizeof(u16));
  float* statsAll = (float*)alloc((3 * 8192 + 1024) * sizeof(float));  // 3 layers banked + fc
  float* h1buf   = (float*)alloc((size_t)MNODE * 64 * sizeof(float));
  float* h2buf   = (float*)alloc((size_t)MNODE * 128 * sizeof(float));
  float* h3buf   = (float*)alloc((size_t)MNODE * 256 * sizeof(float));
  float* pooled  = (float*)alloc(128 * 512 * sizeof(float));
  float* t1raw   = (float*)alloc(128 * 256 * sizeof(float));
  float* t2raw   = (float*)alloc(128 * 128 * sizeof(float));

  float* fcstats = statsAll + 3 * 8192;
  float* fs  = fcstats;
  float* fss = fcstats + 256;
  float* gs  = fcstats + 512;
  float* gss = fcstats + 768;

  (void)hipMemsetAsync(statsAll, 0, (3 * 8192 + 1024) * sizeof(float), stream);

  run_edgeconv<6,   64 >(x,     w11, b11, g11, e11, w12, b12, g12, e12, h1buf,
                         statsAll, L, stream);
  run_edgeconv<64,  128>(h1buf, w21, b21, g21, e21, w22, b22, g22, e22, h2buf,
                         statsAll + 8192, L, stream);
  run_edgeconv<128, 256>(h2buf, w31, b31, g31, e31, w32, b32, g32, e32, h3buf,
                         statsAll + 16384, L, stream);

  pool_kernel<<<dim3(BB), dim3(256), 0, stream>>>(h3buf, pooled);
  fc1_fused<<<dim3(BB), dim3(256), 0, stream>>>(pooled, fw1, fb1, t1raw, fs, fss);
  fc2_fused<<<dim3(BB), dim3(256), 0, stream>>>(t1raw, fs, fss, fg1, fe1, fw2, fb2, t2raw, gs, gss);
  fc3_fused<<<dim3(1), dim3(256), 0, stream>>>(t2raw, gs, gss, fg2, fe2, fw3, fb3, (float*)d_out);
}

// Round 14
// 841.203 us; speedup vs baseline: 1.5956x; 1.0722x over previous
//
#include <hip/hip_runtime.h>
#include <math.h>

#define BB 128
#define NN 128
#define KK 16
#define MEDGE (BB*NN*KK)   // 262144 edges
#define MNODE (BB*NN)      // 16384 nodes

typedef __bf16 bf16x8 __attribute__((ext_vector_type(8)));
typedef float  floatx4 __attribute__((ext_vector_type(4)));
typedef unsigned short u16;
typedef u16 ushort8_alias __attribute__((ext_vector_type(8)));

// ---------------------------------------------------------------- utilities

__device__ __forceinline__ unsigned ord32(float f) {
  unsigned u = __float_as_uint(f);
  return (u & 0x80000000u) ? ~u : (u | 0x80000000u);
}

__device__ __forceinline__ unsigned long long shfl_xor_u64(unsigned long long v, int m) {
  unsigned lo = (unsigned)(v & 0xffffffffull);
  unsigned hi = (unsigned)(v >> 32);
  lo = __shfl_xor(lo, m, 64);
  hi = __shfl_xor(hi, m, 64);
  return (((unsigned long long)hi) << 32) | (unsigned long long)lo;
}

__device__ __forceinline__ u16 bf16_rne_bits(float x) {
  unsigned u = __float_as_uint(x);
  return (u16)((u + 0x7FFF + ((u >> 16) & 1)) >> 16);
}

// ---------------------------------------------------------------- fused kNN (dist + select)
// 2 blocks per batch (64 query rows each). x staged in LDS; after the Gram
// phase the distance matrix D is overlaid onto the SAME buffer (sized as the
// max of both uses — R13 bug was sizing it only for x at Cin=6).
template<int C>
__global__ __launch_bounds__(256) void knn_fused(const float* __restrict__ x,
                                                 int* __restrict__ idx) {
  constexpr int S = C + 2;
  constexpr int DS = NN + 2;
  constexpr int XSZ = (NN * S > 64 * DS) ? NN * S : 64 * DS;   // union sizing
  __shared__ float xs[XSZ];   // x staging, then reused as Dl[64 * DS]
  __shared__ float sq[NN];
  int b = blockIdx.x >> 1, half = blockIdx.x & 1;
  const float* xb = x + (size_t)b * NN * C;
  int tid = threadIdx.x;

  for (int t = tid; t < NN * C; t += 256) {
    int row = t / C, c = t - row * C;
    xs[row * S + c] = xb[t];
  }
  __syncthreads();
  if (tid < NN) {
    const float* xr = xs + tid * S;
    float s = 0.f;
    for (int c = 0; c < C; ++c) s = fmaf(xr[c], xr[c], s);
    sq[tid] = s;
  }
  __syncthreads();

  // dist: 64 rows x 128 cols; thread = 8 rows x 4 cols (in registers)
  int rg = tid >> 5, cg = tid & 31;
  int r0 = half * 64 + rg * 8;
  float acc[8][4];
#pragma unroll
  for (int i = 0; i < 8; ++i)
#pragma unroll
    for (int j = 0; j < 4; ++j) acc[i][j] = 0.f;
  for (int c = 0; c < C; c += 2) {
    float2 av[8], bv[4];
#pragma unroll
    for (int i = 0; i < 8; ++i) av[i] = *(const float2*)&xs[(r0 + i) * S + c];
#pragma unroll
    for (int j = 0; j < 4; ++j) bv[j] = *(const float2*)&xs[(cg + 32 * j) * S + c];
#pragma unroll
    for (int i = 0; i < 8; ++i)
#pragma unroll
      for (int j = 0; j < 4; ++j) {
        acc[i][j] = fmaf(av[i].x, bv[j].x, acc[i][j]);
        acc[i][j] = fmaf(av[i].y, bv[j].y, acc[i][j]);
      }
  }
  // finish dist in registers (sq is separate storage), then overlay D onto xs
  float dv[8][4];
#pragma unroll
  for (int i = 0; i < 8; ++i) {
    float sn = sq[r0 + i];
#pragma unroll
    for (int j = 0; j < 4; ++j) dv[i][j] = sn - 2.f * acc[i][j] + sq[cg + 32 * j];
  }
  __syncthreads();  // all reads of xs complete
  float* Dl = xs;
#pragma unroll
  for (int i = 0; i < 8; ++i)
#pragma unroll
    for (int j = 0; j < 4; ++j)
      Dl[(rg * 8 + i) * DS + (cg + 32 * j)] = dv[i][j];
  __syncthreads();

  int lane = tid & 63, wv = tid >> 6;
  for (int t = 0; t < 16; ++t) {
    int lr = wv * 16 + t;
    int nd = b * NN + half * 64 + lr;
    unsigned long long key[2];
    key[0] = (((unsigned long long)ord32(Dl[lr * DS + lane])) << 32) | (unsigned)lane;
    key[1] = (((unsigned long long)ord32(Dl[lr * DS + lane + 64])) << 32) | (unsigned)(lane + 64);
    int* out = idx + (size_t)nd * KK;
    for (int r = 0; r < KK; ++r) {
      unsigned long long mk = key[0] < key[1] ? key[0] : key[1];
#pragma unroll
      for (int off = 32; off > 0; off >>= 1) {
        unsigned long long o = shfl_xor_u64(mk, off);
        if (o < mk) mk = o;
      }
      int wm = (int)(mk & 0xffffffffu);
      if (lane == 0) out[r] = wm;
      if ((wm & 63) == lane) key[wm >> 6] = ~0ull;
    }
  }
}

// ---------------------------------------------------------------- node GEMM (scalar, layer-1 only)
__global__ __launch_bounds__(256) void node_gemm(const float* __restrict__ x,
                                                 const float* __restrict__ W,
                                                 float* __restrict__ p, float* __restrict__ q,
                                                 int Cin, int Cout) {
  int c = threadIdx.x;
  __shared__ float xr[128];
  for (int r = 0; r < 8; ++r) {
    int row = blockIdx.x * 8 + r;
    __syncthreads();
    for (int i = c; i < Cin; i += blockDim.x) xr[i] = x[(size_t)row * Cin + i];
    __syncthreads();
    float a = 0.f, qv = 0.f;
    for (int i = 0; i < Cin; ++i) {
      float xv = xr[i];
      a  = fmaf(xv, W[i * Cout + c], a);
      qv = fmaf(xv, W[(Cin + i) * Cout + c], qv);
    }
    p[(size_t)row * Cout + c] = a - qv;
    q[(size_t)row * Cout + c] = qv;
  }
}

// ---------------------------------------------------------------- W1 packing (16x16x32 layout)
template<int K, int N>
__global__ __launch_bounds__(256) void pack_w1_16(const float* __restrict__ W1,
                                                  u16* __restrict__ Wh, u16* __restrict__ Wl) {
  int t = blockIdx.x * 256 + threadIdx.x;
  if (t >= K * N) return;
  constexpr int C = N / 2;
  constexpr int NT = N / 16;
  int j = t & 7, lane = (t >> 3) & 63, tile = t >> 9;
  int nt = tile % NT, kt = tile / NT;
  int row = kt * 32 + (lane >> 4) * 8 + j;
  int col = nt * 16 + (lane & 15);
  float w;
  if (col < C) w = W1[row * C + col] - W1[(K + row) * C + col];
  else         w = W1[(K + row) * C + (col - C)];
  u16 h = bf16_rne_bits(w);
  float hf = __uint_as_float(((unsigned)h) << 16);
  Wh[t] = h;
  Wl[t] = bf16_rne_bits(w - hf);
}

// ---------------------------------------------------------------- node GEMM v2 (v9-style)
template<int K, int N>
__global__ __launch_bounds__(512, 4) void node_gemm_v2(
    const float* __restrict__ x, const u16* __restrict__ Wh, const u16* __restrict__ Wl,
    float* __restrict__ p, float* __restrict__ q) {
  constexpr int C = N / 2;
  constexpr int KT = K / 32;
  constexpr int NT = N / 16;
  constexpr int NCOL = 64, NTS = 4;
  constexpr int NSLICE = N / 64;
  constexpr int CCH = KT * NTS * 2 * 64;
  __shared__ __align__(16) u16 Bst[CCH * 8];

  int tid = threadIdx.x, lane = tid & 63, wv = tid >> 6;
  int r = lane & 15, kseg = lane >> 4;
  int g = blockIdx.x / NSLICE, slice = blockIdx.x % NSLICE;
  int rowBase = g * 128 + wv * 16;
  const float* xr = x + (size_t)(rowBase + r) * K;

  for (int i = tid; i < CCH; i += 512) {
    int c = i & 63, h = (i >> 6) & 1, rest = i >> 7;
    int nt = rest % NTS, kt = rest / NTS;
    const ushort8_alias* src = h ? (const ushort8_alias*)Wl : (const ushort8_alias*)Wh;
    ((ushort8_alias*)Bst)[i] = src[((size_t)kt * NT + slice * NTS + nt) * 64 + c];
  }
  __syncthreads();

  floatx4 acc[NTS];
#pragma unroll
  for (int nt = 0; nt < NTS; ++nt) acc[nt] = {0.f, 0.f, 0.f, 0.f};

#pragma unroll
  for (int kt = 0; kt < KT; ++kt) {
    int c0 = kt * 32 + kseg * 8;
    float4 xa = *(const float4*)(xr + c0);
    float4 xb = *(const float4*)(xr + c0 + 4);
    float hv[8] = {xa.x, xa.y, xa.z, xa.w, xb.x, xb.y, xb.z, xb.w};
    bf16x8 ah, al;
#pragma unroll
    for (int t = 0; t < 8; ++t) {
      __bf16 hb = (__bf16)hv[t];
      ah[t] = hb;
      al[t] = (__bf16)(hv[t] - (float)hb);
    }
#pragma unroll
    for (int nt = 0; nt < NTS; ++nt) {
      int base = (kt * NTS + nt) * 128 + lane;
      bf16x8 bh = __builtin_bit_cast(bf16x8, ((const ushort8_alias*)Bst)[base]);
      bf16x8 bl = __builtin_bit_cast(bf16x8, ((const ushort8_alias*)Bst)[base + 64]);
      acc[nt] = __builtin_amdgcn_mfma_f32_16x16x32_bf16(ah, bh, acc[nt], 0, 0, 0);
      acc[nt] = __builtin_amdgcn_mfma_f32_16x16x32_bf16(al, bh, acc[nt], 0, 0, 0);
      acc[nt] = __builtin_amdgcn_mfma_f32_16x16x32_bf16(ah, bl, acc[nt], 0, 0, 0);
    }
  }

#pragma unroll
  for (int nt = 0; nt < NTS; ++nt) {
    int n = slice * NCOL + nt * 16 + r;
    float* dst = (n < C) ? p : q;
    int col = (n < C) ? n : n - C;
#pragma unroll
    for (int gi = 0; gi < 4; ++gi) {
      int row = rowBase + kseg * 4 + gi;
      dst[(size_t)row * C + col] = acc[nt][gi];
    }
  }
}

// ---------------------------------------------------------------- BN1 stats (banked atomics)
template<int C>
__global__ __launch_bounds__(256) void edge_stats1v(const float* __restrict__ p,
                                                    const float* __restrict__ q,
                                                    const float* __restrict__ b1,
                                                    const int* __restrict__ idx,
                                                    float* __restrict__ statsL) {
  constexpr int G = C / 4;
  constexpr int KL = 64 / G;
  int tid = threadIdx.x, lane = tid & 63, wv = tid >> 6;
  int nd = blockIdx.x * 4 + wv;
  int b = nd >> 7;
  int g = lane % G, kl = lane / G;
  int bank = blockIdx.x & 7;

  __shared__ float sS[C], sSS[C];
  if (tid < C) { sS[tid] = 0.f; sSS[tid] = 0.f; }
  __syncthreads();

  const float* pr = p + (size_t)nd * C;
  float4 pv = *(const float4*)(pr + g * 4);
  float4 bv = *(const float4*)(b1 + g * 4);
  pv.x += bv.x; pv.y += bv.y; pv.z += bv.z; pv.w += bv.w;
  float4 s = {0, 0, 0, 0}, ss = {0, 0, 0, 0};
  const int* id = idx + (size_t)nd * KK;
#pragma unroll
  for (int k0 = 0; k0 < KK; k0 += KL) {
    int j = id[k0 + kl];
    float4 q4 = *(const float4*)(q + (size_t)(b * NN + j) * C + g * 4);
    float y;
    y = pv.x + q4.x; s.x += y; ss.x = fmaf(y, y, ss.x);
    y = pv.y + q4.y; s.y += y; ss.y = fmaf(y, y, ss.y);
    y = pv.z + q4.z; s.z += y; ss.z = fmaf(y, y, ss.z);
    y = pv.w + q4.w; s.w += y; ss.w = fmaf(y, y, ss.w);
  }
#pragma unroll
  for (int off = G; off < 64; off <<= 1) {
    s.x += __shfl_xor(s.x, off); ss.x += __shfl_xor(ss.x, off);
    s.y += __shfl_xor(s.y, off); ss.y += __shfl_xor(ss.y, off);
    s.z += __shfl_xor(s.z, off); ss.z += __shfl_xor(ss.z, off);
    s.w += __shfl_xor(s.w, off); ss.w += __shfl_xor(ss.w, off);
  }
  if (kl == 0) {
    atomicAdd(&sS[g * 4 + 0], s.x); atomicAdd(&sSS[g * 4 + 0], ss.x);
    atomicAdd(&sS[g * 4 + 1], s.y); atomicAdd(&sSS[g * 4 + 1], ss.y);
    atomicAdd(&sS[g * 4 + 2], s.z); atomicAdd(&sSS[g * 4 + 2], ss.z);
    atomicAdd(&sS[g * 4 + 3], s.w); atomicAdd(&sSS[g * 4 + 3], ss.w);
  }
  __syncthreads();
  if (tid < C) {
    atomicAdd(&statsL[bank * 256 + tid], sS[tid]);
    atomicAdd(&statsL[2048 + bank * 256 + tid], sSS[tid]);
  }
}

// ---------------------------------------------------------------- W2 packing (16x16x32)
template<int C>
__global__ __launch_bounds__(256) void pack_w2(const float* __restrict__ W,
                                               u16* __restrict__ Wh, u16* __restrict__ Wl) {
  int t = blockIdx.x * 256 + threadIdx.x;
  if (t >= C * C) return;
  constexpr int NT = C / 16;
  int j = t & 7, lane = (t >> 3) & 63, tile = t >> 9;
  int nt = tile % NT, kt = tile / NT;
  int row = kt * 32 + (lane >> 4) * 8 + j;
  int col = nt * 16 + (lane & 15);
  float w = W[row * C + col];
  u16 h = bf16_rne_bits(w);
  float hf = __uint_as_float(((unsigned)h) << 16);
  Wh[t] = h;
  Wl[t] = bf16_rne_bits(w - hf);
}

// ---------------------------------------------------------------- MFMA edge GEMM2 v10
template<int C, int NCOL, int CK>
__global__ __launch_bounds__(512, (C > 128) ? 2 : 4) void edge_gemm2_v10(
    const float* __restrict__ p, const float* __restrict__ q,
    const int* __restrict__ idx,
    const float* __restrict__ statsL,
    const float* __restrict__ g1, const float* __restrict__ e1,
    const float* __restrict__ b1,
    const u16* __restrict__ Wh, const u16* __restrict__ Wl,
    const float* __restrict__ b2,
    float* __restrict__ zmax, float* __restrict__ zmin,
    float* __restrict__ s2b, float* __restrict__ ss2b) {
  constexpr int KT = C / 32;
  constexpr int NT = C / 16;
  constexpr int NSLICE = C / NCOL;
  constexpr int NTS = NCOL / 16;
  constexpr int NWIN = KT / CK;
  constexpr int CCH = CK * NTS * 2 * 64;
  __shared__ __align__(16) u16 Bst[CCH * 8];
  __shared__ float sScl[C], sShf[C];
  __shared__ float sS[NCOL], sSS[NCOL];

  int tid = threadIdx.x, lane = tid & 63, wv = tid >> 6;
  int r = lane & 15, kseg = lane >> 4;

  int g = blockIdx.x / NSLICE, slice = blockIdx.x % NSLICE;
  int u = g >> 3, xcd = g & 7;
  int b = xcd + 8 * (u >> 4);
  int nodeBase = b * NN + (u & 15) * 8;
  int nd = nodeBase + wv;

  if (tid < C) {
    float s = 0.f, ssum = 0.f;
#pragma unroll
    for (int k = 0; k < 8; ++k) {
      s += statsL[k * 256 + tid];
      ssum += statsL[2048 + k * 256 + tid];
    }
    float mean = s / (float)MEDGE;
    float var = ssum / (float)MEDGE - mean * mean;
    if (var < 0.f) var = 0.f;
    float sc = g1[tid] * rsqrtf(var + 1e-5f);
    sScl[tid] = sc;
    sShf[tid] = e1[tid] - mean * sc + sc * b1[tid];
  }
  if (tid < NCOL) { sS[tid] = 0.f; sSS[tid] = 0.f; }

  int j = idx[(size_t)nd * KK + r];
  const float* pr = p + (size_t)nd * C;
  const float* qr = q + (size_t)(b * NN + j) * C;

  floatx4 acc[NTS];
#pragma unroll
  for (int nt = 0; nt < NTS; ++nt) {
    float bv = b2[slice * NCOL + nt * 16 + r];
    acc[nt] = {bv, bv, bv, bv};
  }

#pragma unroll
  for (int w = 0; w < NWIN; ++w) {
    if (w > 0) __syncthreads();
    for (int i = tid; i < CCH; i += 512) {
      int c = i & 63, h = (i >> 6) & 1, rest = i >> 7;
      int nt = rest % NTS, kk = rest / NTS;
      const ushort8_alias* src = h ? (const ushort8_alias*)Wl : (const ushort8_alias*)Wh;
      ((ushort8_alias*)Bst)[i] = src[((size_t)(w * CK + kk) * NT + slice * NTS + nt) * 64 + c];
    }
    __syncthreads();

#pragma unroll
    for (int kk = 0; kk < CK; ++kk) {
      int c0 = (w * CK + kk) * 32 + kseg * 8;
      float4 pa = *(const float4*)(pr + c0);
      float4 pb = *(const float4*)(pr + c0 + 4);
      float4 qa = *(const float4*)(qr + c0);
      float4 qb = *(const float4*)(qr + c0 + 4);
      float4 sa = *(const float4*)(sScl + c0);
      float4 sb = *(const float4*)(sScl + c0 + 4);
      float4 ta = *(const float4*)(sShf + c0);
      float4 tb = *(const float4*)(sShf + c0 + 4);
      float hv[8];
      hv[0] = fmaxf(fmaf(pa.x + qa.x, sa.x, ta.x), 0.f);
      hv[1] = fmaxf(fmaf(pa.y + qa.y, sa.y, ta.y), 0.f);
      hv[2] = fmaxf(fmaf(pa.z + qa.z, sa.z, ta.z), 0.f);
      hv[3] = fmaxf(fmaf(pa.w + qa.w, sa.w, ta.w), 0.f);
      hv[4] = fmaxf(fmaf(pb.x + qb.x, sb.x, tb.x), 0.f);
      hv[5] = fmaxf(fmaf(pb.y + qb.y, sb.y, tb.y), 0.f);
      hv[6] = fmaxf(fmaf(pb.z + qb.z, sb.z, tb.z), 0.f);
      hv[7] = fmaxf(fmaf(pb.w + qb.w, sb.w, tb.w), 0.f);
      bf16x8 ah, al;
#pragma unroll
      for (int t = 0; t < 8; ++t) {
        __bf16 hb = (__bf16)hv[t];
        ah[t] = hb;
        al[t] = (__bf16)(hv[t] - (float)hb);
      }
#pragma unroll
      for (int nt = 0; nt < NTS; ++nt) {
        int base = (kk * NTS + nt) * 128 + lane;
        bf16x8 bh = __builtin_bit_cast(bf16x8, ((const ushort8_alias*)Bst)[base]);
        bf16x8 bl = __builtin_bit_cast(bf16x8, ((const ushort8_alias*)Bst)[base + 64]);
        acc[nt] = __builtin_amdgcn_mfma_f32_16x16x32_bf16(ah, bh, acc[nt], 0, 0, 0);
        acc[nt] = __builtin_amdgcn_mfma_f32_16x16x32_bf16(al, bh, acc[nt], 0, 0, 0);
        acc[nt] = __builtin_amdgcn_mfma_f32_16x16x32_bf16(ah, bl, acc[nt], 0, 0, 0);
      }
    }
  }

  int bank = blockIdx.x & 7;
#pragma unroll
  for (int nt = 0; nt < NTS; ++nt) {
    float s = 0.f, ss = 0.f, mx = -INFINITY, mn = INFINITY;
#pragma unroll
    for (int gi = 0; gi < 4; ++gi) {
      float z = acc[nt][gi];
      s += z; ss = fmaf(z, z, ss);
      mx = fmaxf(mx, z); mn = fminf(mn, z);
    }
    mx = fmaxf(mx, __shfl_xor(mx, 16)); mn = fminf(mn, __shfl_xor(mn, 16));
    s += __shfl_xor(s, 16); ss += __shfl_xor(ss, 16);
    mx = fmaxf(mx, __shfl_xor(mx, 32)); mn = fminf(mn, __shfl_xor(mn, 32));
    s += __shfl_xor(s, 32); ss += __shfl_xor(ss, 32);
    if (kseg == 0) {
      int colL = nt * 16 + r;
      int col = slice * NCOL + colL;
      zmax[(size_t)nd * C + col] = mx;
      zmin[(size_t)nd * C + col] = mn;
      atomicAdd(&sS[colL], s);
      atomicAdd(&sSS[colL], ss);
    }
  }
  __syncthreads();
  if (tid < NCOL) {
    atomicAdd(&s2b[bank * 256 + slice * NCOL + tid], sS[tid]);
    atomicAdd(&ss2b[bank * 256 + slice * NCOL + tid], sSS[tid]);
  }
}

// ---------------------------------------------------------------- finalize (banked BN2 params)
__global__ __launch_bounds__(256) void finalize2_kernel(const float* __restrict__ zmax,
                                                        const float* __restrict__ zmin,
                                                        const float* __restrict__ s2b,
                                                        const float* __restrict__ ss2b,
                                                        const float* __restrict__ g2,
                                                        const float* __restrict__ e2,
                                                        float* __restrict__ out, int Cmask) {
  int t = blockIdx.x * 256 + threadIdx.x;
  int c = t & Cmask;
  float s = 0.f, ss = 0.f;
#pragma unroll
  for (int k = 0; k < 8; ++k) {
    s += s2b[k * 256 + c];
    ss += ss2b[k * 256 + c];
  }
  float mean = s / (float)MEDGE;
  float var = ss / (float)MEDGE - mean * mean;
  if (var < 0.f) var = 0.f;
  float scl = g2[c] * rsqrtf(var + 1e-5f);
  float shf = e2[c] - mean * scl;
  float v = (scl >= 0.f) ? zmax[t] : zmin[t];
  out[t] = fmaxf(fmaf(v, scl, shf), 0.f);
}

// ---------------------------------------------------------------- pooling
__global__ __launch_bounds__(256) void pool_kernel(const float* __restrict__ h,
                                                   float* __restrict__ pooled) {
  int b = blockIdx.x, c = threadIdx.x;
  float s = 0.f, mx = -INFINITY;
  for (int n = 0; n < NN; ++n) {
    float v = h[(size_t)(b * NN + n) * 256 + c];
    s += v;
    mx = fmaxf(mx, v);
  }
  pooled[b * 512 + c] = s * (1.f / 128.f);
  pooled[b * 512 + 256 + c] = mx;
}

// ---------------------------------------------------------------- FC tail
__global__ __launch_bounds__(256) void fc1_fused(const float* __restrict__ pooled,
                                                 const float* __restrict__ W,
                                                 const float* __restrict__ bias,
                                                 float* __restrict__ t1raw,
                                                 float* __restrict__ fs, float* __restrict__ fss) {
  int b = blockIdx.x, c = threadIdx.x;
  __shared__ float row[512];
  row[c] = pooled[b * 512 + c];
  row[c + 256] = pooled[b * 512 + 256 + c];
  __syncthreads();
  float acc = bias[c];
  for (int i = 0; i < 512; ++i) acc = fmaf(row[i], W[i * 256 + c], acc);
  t1raw[b * 256 + c] = acc;
  atomicAdd(&fs[c], acc);
  atomicAdd(&fss[c], acc * acc);
}

__global__ __launch_bounds__(256) void fc2_fused(const float* __restrict__ t1raw,
                                                 const float* __restrict__ fs,
                                                 const float* __restrict__ fss,
                                                 const float* __restrict__ g1,
                                                 const float* __restrict__ e1,
                                                 const float* __restrict__ W,
                                                 const float* __restrict__ bias,
                                                 float* __restrict__ t2raw,
                                                 float* __restrict__ gs, float* __restrict__ gss) {
  int b = blockIdx.x, c = threadIdx.x;
  __shared__ float row[256];
  {
    float mean = fs[c] / 128.f;
    float var = fss[c] / 128.f - mean * mean;
    if (var < 0.f) var = 0.f;
    float scl = g1[c] * rsqrtf(var + 1e-5f);
    float shf = e1[c] - mean * scl;
    row[c] = fmaxf(fmaf(t1raw[b * 256 + c], scl, shf), 0.f);
  }
  __syncthreads();
  if (c < 128) {
    float acc = bias[c];
    for (int i = 0; i < 256; ++i) acc = fmaf(row[i], W[i * 128 + c], acc);
    t2raw[b * 128 + c] = acc;
    atomicAdd(&gs[c], acc);
    atomicAdd(&gss[c], acc * acc);
  }
}

__global__ __launch_bounds__(256) void fc3_fused(const float* __restrict__ t2raw,
                                                 const float* __restrict__ gs,
                                                 const float* __restrict__ gss,
                                                 const float* __restrict__ g2,
                                                 const float* __restrict__ e2,
                                                 const float* __restrict__ W,
                                                 const float* __restrict__ bias,
                                                 float* __restrict__ out) {
  __shared__ float row[128 * 2];
  int t = threadIdx.x;
  if (t < 128) {
    float mean = gs[t] / 128.f;
    float var = gss[t] / 128.f - mean * mean;
    if (var < 0.f) var = 0.f;
    float scl = g2[t] * rsqrtf(var + 1e-5f);
    row[t] = scl;
    row[128 + t] = e2[t] - mean * scl;
  }
  __syncthreads();
  int b = t >> 1, jj = t & 1;
  float acc = bias[jj];
  for (int r = 0; r < 128; ++r) {
    float v = fmaxf(fmaf(t2raw[b * 128 + r], row[r], row[128 + r]), 0.f);
    acc = fmaf(v, W[r * 2 + jj], acc);
  }
  out[t] = acc;
}

// ---------------------------------------------------------------- per-layer driver

struct LayerPtrs {
  int* idx; float *p, *q, *zmx, *zmn;
  u16 *Wh, *Wl, *Wh1, *Wl1;
};

template<int Cin, int C>
static void run_edgeconv(const float* xin,
                         const float* W1, const float* b1, const float* g1, const float* e1,
                         const float* W2, const float* b2, const float* g2, const float* e2,
                         float* hout, float* statsL, const LayerPtrs& L, hipStream_t stream) {
  float* s2b = statsL + 4096;
  float* ss2b = statsL + 6144;

  knn_fused<Cin><<<dim3(BB * 2), dim3(256), 0, stream>>>(xin, L.idx);
  if constexpr (Cin >= 16) {
    pack_w1_16<Cin, 2 * C><<<dim3((Cin * 2 * C + 255) / 256), dim3(256), 0, stream>>>(W1, L.Wh1, L.Wl1);
    constexpr int NSL1 = (2 * C) / 64;
    node_gemm_v2<Cin, 2 * C><<<dim3((MNODE / 128) * NSL1), dim3(512), 0, stream>>>(
        xin, L.Wh1, L.Wl1, L.p, L.q);
  } else {
    node_gemm<<<dim3(MNODE / 8), dim3(C), 0, stream>>>(xin, W1, L.p, L.q, Cin, C);
  }
  pack_w2<C><<<dim3((C * C + 255) / 256), dim3(256), 0, stream>>>(W2, L.Wh, L.Wl);
  edge_stats1v<C><<<dim3(MNODE / 4), dim3(256), 0, stream>>>(L.p, L.q, b1, L.idx, statsL);
  constexpr int NCOL = (C == 256) ? 128 : 64;
  constexpr int CKW = (C == 64) ? 2 : 4;
  constexpr int NSL = C / NCOL;
  edge_gemm2_v10<C, NCOL, CKW><<<dim3((MNODE / 8) * NSL), dim3(512), 0, stream>>>(
      L.p, L.q, L.idx, statsL, g1, e1, b1, L.Wh, L.Wl, b2, L.zmx, L.zmn, s2b, ss2b);
  finalize2_kernel<<<dim3(MNODE * C / 256), dim3(256), 0, stream>>>(
      L.zmx, L.zmn, s2b, ss2b, g2, e2, hout, C - 1);
}

// ---------------------------------------------------------------- launch

extern "C" void kernel_launch(void* const* d_in, const int* in_sizes, int n_in,
                              void* d_out, int out_size, void* d_ws, size_t ws_size,
                              hipStream_t stream) {
  const float* x   = (const float*)d_in[0];
  const float* w11 = (const float*)d_in[1];
  const float* b11 = (const float*)d_in[2];
  const float* g11 = (const float*)d_in[3];
  const float* e11 = (const float*)d_in[4];
  const float* w12 = (const float*)d_in[5];
  const float* b12 = (const float*)d_in[6];
  const float* g12 = (const float*)d_in[7];
  const float* e12 = (const float*)d_in[8];
  const float* w21 = (const float*)d_in[9];
  const float* b21 = (const float*)d_in[10];
  const float* g21 = (const float*)d_in[11];
  const float* e21 = (const float*)d_in[12];
  const float* w22 = (const float*)d_in[13];
  const float* b22 = (const float*)d_in[14];
  const float* g22 = (const float*)d_in[15];
  const float* e22 = (const float*)d_in[16];
  const float* w31 = (const float*)d_in[17];
  const float* b31 = (const float*)d_in[18];
  const float* g31 = (const float*)d_in[19];
  const float* e31 = (const float*)d_in[20];
  const float* w32 = (const float*)d_in[21];
  const float* b32 = (const float*)d_in[22];
  const float* g32 = (const float*)d_in[23];
  const float* e32 = (const float*)d_in[24];
  const float* fw1 = (const float*)d_in[25];
  const float* fb1 = (const float*)d_in[26];
  const float* fg1 = (const float*)d_in[27];
  const float* fe1 = (const float*)d_in[28];
  const float* fw2 = (const float*)d_in[29];
  const float* fb2 = (const float*)d_in[30];
  const float* fg2 = (const float*)d_in[31];
  const float* fe2 = (const float*)d_in[32];
  const float* fw3 = (const float*)d_in[33];
  const float* fb3 = (const float*)d_in[34];

  char* wsb = (char*)d_ws;
  size_t o = 0;
  auto alloc = [&](size_t bytes) -> void* {
    void* r = wsb + o;
    o += (bytes + 255) & ~(size_t)255;
    return r;
  };
  LayerPtrs L;
  L.idx   = (int*)  alloc((size_t)MNODE * KK * sizeof(int));
  L.p     = (float*)alloc((size_t)MNODE * 256 * sizeof(float));
  L.q     = (float*)alloc((size_t)MNODE * 256 * sizeof(float));
  L.zmx   = (float*)alloc((size_t)MNODE * 256 * sizeof(float));
  L.zmn   = (float*)alloc((size_t)MNODE * 256 * sizeof(float));
  L.Wh    = (u16*)  alloc((size_t)256 * 256 * sizeof(u16));
  L.Wl    = (u16*)  alloc((size_t)256 * 256 * sizeof(u16));
  L.Wh1   = (u16*)  alloc((size_t)128 * 512 * sizeof(u16));
  L.Wl1   = (u16*)  alloc((size_t)128 * 512 * sizeof(u16));
  float* statsAll = (float*)alloc((3 * 8192 + 1024) * sizeof(float));
  float* h1buf   = (float*)alloc((size_t)MNODE * 64 * sizeof(float));
  float* h2buf   = (float*)alloc((size_t)MNODE * 128 * sizeof(float));
  float* h3buf   = (float*)alloc((size_t)MNODE * 256 * sizeof(float));
  float* pooled  = (float*)alloc(128 * 512 * sizeof(float));
  float* t1raw   = (float*)alloc(128 * 256 * sizeof(float));
  float* t2raw   = (float*)alloc(128 * 128 * sizeof(float));

  float* fcstats = statsAll + 3 * 8192;
  float* fs  = fcstats;
  float* fss = fcstats + 256;
  float* gs  = fcstats + 512;
  float* gss = fcstats + 768;

  (void)hipMemsetAsync(statsAll, 0, (3 * 8192 + 1024) * sizeof(float), stream);

  run_edgeconv<6,   64 >(x,     w11, b11, g11, e11, w12, b12, g12, e12, h1buf,
                         statsAll, L, stream);
  run_edgeconv<64,  128>(h1buf, w21, b21, g21, e21, w22, b22, g22, e22, h2buf,
                         statsAll + 8192, L, stream);
  run_edgeconv<128, 256>(h2buf, w31, b31, g31, e31, w32, b32, g32, e32, h3buf,
                         statsAll + 16384, L, stream);

  pool_kernel<<<dim3(BB), dim3(256), 0, stream>>>(h3buf, pooled);
  fc1_fused<<<dim3(BB), dim3(256), 0, stream>>>(pooled, fw1, fb1, t1raw, fs, fss);
  fc2_fused<<<dim3(BB), dim3(256), 0, stream>>>(t1raw, fs, fss, fg1, fe1, fw2, fb2, t2raw, gs, gss);
  fc3_fused<<<dim3(1), dim3(256), 0, stream>>>(t2raw, gs, gss, fg2, fe2, fw3, fb3, (float*)d_out);
}